// Round 1
// baseline (870.075 us; speedup 1.0000x reference)
//
#include <hip/hip_runtime.h>
#include <math.h>

#define Bb 2
#define Ss 1500
#define Nn 1280
#define Hh 20
#define Dd 64
#define Rr 32

// ---------------------------------------------------------------------------
// ws layout (floats):
//   wm    [0)        20*32*32 = 20480   (Wq2h @ Wk2h, pre-scaled by 1/8)
//   b2s   [20480)    20*32    = 640     (bq @ Wk2h,  pre-scaled by 1/8)
//   xp    [21120)    2*1500*96 = 288000 (q1|k1|v1 concat per row)
//   vh    [309120)   2*20*1500*64 = 3840000
//   kb    [4149120)  2*20*1500 = 60000
//   wv    [4209120)  2*1500*1280 = 3840000 (attn out + bv)
//   tbuf  [8049120)  2*1500*32 = 96000
//   total 8145120 floats = 32.6 MB
// ---------------------------------------------------------------------------

// K1: Wm[h,r,t] = 1/8 * sum_d Wq2[(h*64+d)*32+r] * Wk2[(h*64+d)*32+t]
//     b2s[h,t]  = 1/8 * sum_d bq[h*64+d] * Wk2[(h*64+d)*32+t]
__global__ void prep_wm_kernel(const float* __restrict__ Wq2, const float* __restrict__ Wk2,
                               const float* __restrict__ bq, float* __restrict__ wm,
                               float* __restrict__ b2s) {
  int h = blockIdx.x, tid = threadIdx.x;
  __shared__ float q2s[2048], k2s[2048], bqs[64];
  for (int e = tid; e < 2048; e += 256) {
    q2s[e] = Wq2[h * 2048 + e];   // layout [d][r]
    k2s[e] = Wk2[h * 2048 + e];   // layout [d][t]
  }
  if (tid < 64) bqs[tid] = bq[h * 64 + tid];
  __syncthreads();
  for (int e = tid; e < 1024; e += 256) {
    int r = e >> 5, t = e & 31;
    float s = 0.f;
    #pragma unroll 16
    for (int d = 0; d < 64; ++d) s += q2s[d * 32 + r] * k2s[d * 32 + t];
    wm[h * 1024 + r * 32 + t] = s * 0.125f;
  }
  if (tid < 32) {
    float s = 0.f;
    #pragma unroll 16
    for (int d = 0; d < 64; ++d) s += bqs[d] * k2s[d * 32 + tid];
    b2s[h * 32 + tid] = s * 0.125f;
  }
}

// K2: xp[row][0:32]=q1, [32:64]=k1, [64:96]=v1 ; row = b*S+s, dot over N=1280
__global__ void proj_qkv_kernel(const float* __restrict__ x, const float* __restrict__ Wq1,
                                const float* __restrict__ Wk1, const float* __restrict__ Wv1,
                                float* __restrict__ xp) {
  __shared__ __align__(16) float xs[8 * 1280];
  int tid = threadIdx.x;
  int rowbase = blockIdx.x * 8;  // 3000 rows / 8 = 375 blocks exact
  const float4* xg = (const float4*)(x + (size_t)rowbase * 1280);
  float4* xs4 = (float4*)xs;
  for (int e = tid; e < 2560; e += 256) xs4[e] = xg[e];
  __syncthreads();
  int wave = tid >> 6, lane = tid & 63;
  for (int o = wave; o < 96; o += 4) {
    const float* wr = (o < 32) ? (Wq1 + o * 1280)
                               : ((o < 64) ? (Wk1 + (o - 32) * 1280) : (Wv1 + (o - 64) * 1280));
    const float4* w4 = (const float4*)wr;
    float acc[8];
    #pragma unroll
    for (int r = 0; r < 8; ++r) acc[r] = 0.f;
    #pragma unroll
    for (int it = 0; it < 5; ++it) {
      float4 w = w4[it * 64 + lane];
      #pragma unroll
      for (int r = 0; r < 8; ++r) {
        float4 xv = *(const float4*)&xs[r * 1280 + (it * 64 + lane) * 4];
        acc[r] += w.x * xv.x + w.y * xv.y + w.z * xv.z + w.w * xv.w;
      }
    }
    #pragma unroll
    for (int off = 32; off > 0; off >>= 1) {
      #pragma unroll
      for (int r = 0; r < 8; ++r) acc[r] += __shfl_down(acc[r], off, 64);
    }
    if (lane == 0) {
      #pragma unroll
      for (int r = 0; r < 8; ++r) xp[(size_t)(rowbase + r) * 96 + o] = acc[r];
    }
  }
}

// K3: vh[b,h,j,d] = sum_r v1[b,j,r] * Wv2[(h*64+d)*32+r];  kb[b,h,j] = sum_t k1[b,j,t]*b2s[h,t]
__global__ void prep_vh_kb_kernel(const float* __restrict__ xp, const float* __restrict__ Wv2,
                                  const float* __restrict__ b2s, float* __restrict__ vh,
                                  float* __restrict__ kb) {
  int jt = blockIdx.x, h = blockIdx.y, b = blockIdx.z;
  int j0 = jt * 64, tid = threadIdx.x;
  __shared__ float v1s[64 * 33];
  __shared__ float k1s[64 * 33];
  __shared__ float wvs[2048];  // [r][d]
  __shared__ float b2sh[32];
  const float* xpb = xp + (size_t)b * Ss * 96;
  for (int e = tid; e < 2048; e += 256) {
    int row = e >> 5, c = e & 31;
    int j = j0 + row;
    float vv = 0.f, kv = 0.f;
    if (j < Ss) { const float* xr = xpb + (size_t)j * 96; vv = xr[64 + c]; kv = xr[32 + c]; }
    v1s[row * 33 + c] = vv;
    k1s[row * 33 + c] = kv;
  }
  for (int e = tid; e < 2048; e += 256) {
    int r = e & 31, d = e >> 5;
    wvs[r * 64 + d] = Wv2[(h * 64 + d) * 32 + r];
  }
  if (tid < 32) b2sh[tid] = b2s[h * 32 + tid];
  __syncthreads();
  int d = tid & 63;
  float* vhb = vh + ((size_t)b * Hh + h) * Ss * 64;
  for (int row = tid >> 6; row < 64; row += 4) {
    float s = 0.f;
    #pragma unroll 8
    for (int r = 0; r < 32; ++r) s += v1s[row * 33 + r] * wvs[r * 64 + d];
    int j = j0 + row;
    if (j < Ss) vhb[(size_t)j * 64 + d] = s;
  }
  if (tid < 64) {
    int j = j0 + tid;
    float s = 0.f;
    #pragma unroll 8
    for (int t = 0; t < 32; ++t) s += k1s[tid * 33 + t] * b2sh[t];
    if (j < Ss) kb[((size_t)b * Hh + h) * Ss + j] = s;
  }
}

// K4: attention. One thread = one query row; 4 groups split j; no-max softmax
// (logits are tame: |s| < ~3). Partials combine by pure addition.
__global__ __launch_bounds__(256) void attn_kernel(
    const float* __restrict__ xp, const float* __restrict__ wm, const float* __restrict__ vh,
    const float* __restrict__ kb, const float* __restrict__ bv, float* __restrict__ wv) {
  int it = blockIdx.x, h = blockIdx.y, b = blockIdx.z;
  int i0 = it * 64;
  int tid = threadIdx.x, grp = tid >> 6, lane = tid & 63;

  // time-multiplexed region: q1S[64][33] (prologue) | kS[64][32]+vS[64][64] (loop) | accO[64][65]+accS[64] (epilogue)
  __shared__ __align__(16) float smem[6144];
  __shared__ float wms[1024];
  __shared__ float kbS[64];

  const float* xpb = xp + (size_t)b * Ss * 96;

  for (int e = tid; e < 2048; e += 256) {
    int row = e >> 5, r = e & 31;
    int i = i0 + row;
    smem[row * 33 + r] = (i < Ss) ? xpb[(size_t)i * 96 + r] : 0.f;
  }
  for (int e = tid; e < 1024; e += 256) wms[e] = wm[h * 1024 + e];
  __syncthreads();

  // qh (scaled) in registers: qh[t] = sum_r q1[i][r] * wm[h][r][t]
  float qh[32];
  #pragma unroll
  for (int t = 0; t < 32; ++t) qh[t] = 0.f;
  for (int r = 0; r < 32; ++r) {
    float qv = smem[lane * 33 + r];
    #pragma unroll
    for (int t = 0; t < 32; ++t) qh[t] += qv * wms[r * 32 + t];
  }

  float acc[64];
  #pragma unroll
  for (int d = 0; d < 64; ++d) acc[d] = 0.f;
  float psum = 0.f;

  float* kS = smem;         // [64][32]
  float* vS = smem + 2048;  // [64][64]
  const float* kbb = kb + ((size_t)b * Hh + h) * Ss;
  const float* vhb = vh + ((size_t)b * Hh + h) * Ss * 64;

  for (int j0 = 0; j0 < Ss; j0 += 64) {
    __syncthreads();  // previous tile reads done
    for (int e = tid; e < 2048; e += 256) {
      int row = e >> 5, c = e & 31;
      int j = j0 + row;
      kS[row * 32 + c] = (j < Ss) ? xpb[(size_t)j * 96 + 32 + c] : 0.f;
    }
    for (int e = tid; e < 4096; e += 256) {
      int row = e >> 6, d = e & 63;
      int j = j0 + row;
      vS[row * 64 + d] = (j < Ss) ? vhb[(size_t)j * 64 + d] : 0.f;
    }
    if (tid < 64) {
      int j = j0 + tid;
      kbS[tid] = (j < Ss) ? kbb[j] : -1e30f;  // exp -> 0 for padded keys
    }
    __syncthreads();

    int jb = grp * 16;  // each group handles 16 of the 64 staged keys
    #pragma unroll 4
    for (int jj = 0; jj < 16; ++jj) {
      int jl = jb + jj;
      float s = kbS[jl];
      const float4* k4 = (const float4*)(kS + jl * 32);
      #pragma unroll
      for (int t4 = 0; t4 < 8; ++t4) {
        float4 kv = k4[t4];
        s += qh[t4 * 4 + 0] * kv.x + qh[t4 * 4 + 1] * kv.y + qh[t4 * 4 + 2] * kv.z +
             qh[t4 * 4 + 3] * kv.w;
      }
      float p = __expf(s);
      psum += p;
      const float4* v4 = (const float4*)(vS + jl * 64);
      #pragma unroll
      for (int d4 = 0; d4 < 16; ++d4) {
        float4 vv = v4[d4];
        acc[d4 * 4 + 0] += p * vv.x;
        acc[d4 * 4 + 1] += p * vv.y;
        acc[d4 * 4 + 2] += p * vv.z;
        acc[d4 * 4 + 3] += p * vv.w;
      }
    }
  }

  __syncthreads();  // all vS/kS reads done; reuse smem for combine
  float* accO = smem;         // [64][65]
  float* accS = smem + 4160;  // [64]
  for (int g = 0; g < 4; ++g) {
    if (grp == g) {
      if (g == 0) {
        accS[lane] = psum;
        #pragma unroll
        for (int d = 0; d < 64; ++d) accO[lane * 65 + d] = acc[d];
      } else {
        accS[lane] += psum;
        #pragma unroll
        for (int d = 0; d < 64; ++d) accO[lane * 65 + d] += acc[d];
      }
    }
    __syncthreads();
  }

  // wv[b][i][h*64+d] = O/sum + bv
  float* wvb = wv + (size_t)b * Ss * 1280 + h * 64;
  for (int e = tid; e < 4096; e += 256) {
    int row = e >> 6, d = e & 63;
    int i = i0 + row;
    if (i < Ss) wvb[(size_t)i * 1280 + d] = accO[row * 65 + d] / accS[row] + bv[h * 64 + d];
  }
}

// K5a: tbuf[row][o] = sum_n wv[row][n] * Wo1[o][n]
__global__ void proj_o1_kernel(const float* __restrict__ wv, const float* __restrict__ Wo1,
                               float* __restrict__ tbuf) {
  __shared__ __align__(16) float xs[8 * 1280];
  int tid = threadIdx.x;
  int rowbase = blockIdx.x * 8;
  const float4* xg = (const float4*)(wv + (size_t)rowbase * 1280);
  float4* xs4 = (float4*)xs;
  for (int e = tid; e < 2560; e += 256) xs4[e] = xg[e];
  __syncthreads();
  int wave = tid >> 6, lane = tid & 63;
  for (int o = wave; o < 32; o += 4) {
    const float4* w4 = (const float4*)(Wo1 + o * 1280);
    float acc[8];
    #pragma unroll
    for (int r = 0; r < 8; ++r) acc[r] = 0.f;
    #pragma unroll
    for (int it = 0; it < 5; ++it) {
      float4 w = w4[it * 64 + lane];
      #pragma unroll
      for (int r = 0; r < 8; ++r) {
        float4 xv = *(const float4*)&xs[r * 1280 + (it * 64 + lane) * 4];
        acc[r] += w.x * xv.x + w.y * xv.y + w.z * xv.z + w.w * xv.w;
      }
    }
    #pragma unroll
    for (int off = 32; off > 0; off >>= 1) {
      #pragma unroll
      for (int r = 0; r < 8; ++r) acc[r] += __shfl_down(acc[r], off, 64);
    }
    if (lane == 0) {
      #pragma unroll
      for (int r = 0; r < 8; ++r) tbuf[(size_t)(rowbase + r) * 32 + o] = acc[r];
    }
  }
}

// K5b: out[row][n] = bo[n] + sum_o tbuf[row][o] * Wo2[n][o]
__global__ void proj_o2_kernel(const float* __restrict__ tbuf, const float* __restrict__ Wo2,
                               const float* __restrict__ bo, float* __restrict__ out) {
  int rb = blockIdx.x, nb = blockIdx.y, tid = threadIdx.x;
  int rowbase = rb * 16, n0 = nb * 256;
  __shared__ float ts[16 * 33];
  __shared__ float wos[256 * 33];
  for (int e = tid; e < 8192; e += 256) {
    int nloc = e >> 5, o = e & 31;
    wos[nloc * 33 + o] = Wo2[(size_t)(n0 + nloc) * 32 + o];
  }
  for (int e = tid; e < 512; e += 256) {
    int row = e >> 5, o = e & 31;
    int gr = rowbase + row;
    ts[row * 33 + o] = (gr < Bb * Ss) ? tbuf[(size_t)gr * 32 + o] : 0.f;
  }
  __syncthreads();
  int n = n0 + tid;
  float bias = bo[n];
  for (int row = 0; row < 16; ++row) {
    int gr = rowbase + row;
    if (gr >= Bb * Ss) break;
    float s = bias;
    #pragma unroll 8
    for (int o = 0; o < 32; ++o) s += ts[row * 33 + o] * wos[tid * 33 + o];
    out[(size_t)gr * 1280 + n] = s;
  }
}

extern "C" void kernel_launch(void* const* d_in, const int* in_sizes, int n_in,
                              void* d_out, int out_size, void* d_ws, size_t ws_size,
                              hipStream_t stream) {
  const float* x   = (const float*)d_in[0];
  const float* Wq1 = (const float*)d_in[1];
  const float* Wq2 = (const float*)d_in[2];
  const float* bq  = (const float*)d_in[3];
  const float* Wk1 = (const float*)d_in[4];
  const float* Wk2 = (const float*)d_in[5];
  // d_in[6] = bk : provably drops out of softmax (row-constant logit shift)
  const float* Wv1 = (const float*)d_in[7];
  const float* Wv2 = (const float*)d_in[8];
  const float* bv  = (const float*)d_in[9];
  const float* Wo1 = (const float*)d_in[10];
  const float* Wo2 = (const float*)d_in[11];
  const float* bo  = (const float*)d_in[12];
  float* out = (float*)d_out;
  float* ws  = (float*)d_ws;

  if (ws_size < (size_t)8145120 * sizeof(float)) return;  // loud failure: out stays poisoned

  float* wm   = ws;
  float* b2s  = ws + 20480;
  float* xp   = ws + 21120;
  float* vh   = ws + 309120;
  float* kb   = ws + 4149120;
  float* wv   = ws + 4209120;
  float* tbuf = ws + 8049120;

  prep_wm_kernel<<<20, 256, 0, stream>>>(Wq2, Wk2, bq, wm, b2s);
  proj_qkv_kernel<<<375, 256, 0, stream>>>(x, Wq1, Wk1, Wv1, xp);
  prep_vh_kb_kernel<<<dim3(24, 20, 2), 256, 0, stream>>>(xp, Wv2, b2s, vh, kb);
  attn_kernel<<<dim3(24, 20, 2), 256, 0, stream>>>(xp, wm, vh, kb, bv, wv);
  proj_o1_kernel<<<375, 256, 0, stream>>>(wv, Wo1, tbuf);
  proj_o2_kernel<<<dim3(188, 5), 256, 0, stream>>>(tbuf, Wo2, bo, out);
}

// Round 2
// 309.143 us; speedup vs baseline: 2.8145x; 2.8145x over previous
//
#include <hip/hip_runtime.h>
#include <math.h>

#define Bb 2
#define Ss 1500
#define SP 1536   // padded S (24 tiles of 64)
#define Nn 1280
#define Hh 20
#define Dd 64
#define Rr 32
#define NT 24     // j/i tiles

typedef __attribute__((ext_vector_type(8))) short short8;
typedef __attribute__((ext_vector_type(4))) float f32x4;

__device__ __forceinline__ unsigned short f2bf(float f) {
  unsigned u = __float_as_uint(f);
  u += 0x7fffu + ((u >> 16) & 1u);
  return (unsigned short)(u >> 16);
}

__device__ __forceinline__ void gload16(const void* g, void* l) {
  __builtin_amdgcn_global_load_lds((const __attribute__((address_space(1))) unsigned int*)g,
                                   (__attribute__((address_space(3))) unsigned int*)l, 16, 0, 0);
}
__device__ __forceinline__ void gload4(const void* g, void* l) {
  __builtin_amdgcn_global_load_lds((const __attribute__((address_space(1))) unsigned int*)g,
                                   (__attribute__((address_space(3))) unsigned int*)l, 4, 0, 0);
}

#define BAR()                                  \
  do {                                         \
    asm volatile("" ::: "memory");             \
    __builtin_amdgcn_s_barrier();              \
    asm volatile("" ::: "memory");             \
  } while (0)

#define VMW(n) asm volatile("s_waitcnt vmcnt(" #n ")" ::: "memory")

// ---------------------------------------------------------------------------
// ws layout (float offsets):
//   wm    0        (20480)   fp32, pre-scaled 1/8
//   b2s   20480    (640)     fp32, pre-scaled 1/8
//   xp    21120    (288000)  fp32 q1|k1|v1 per row
//   kb    309120   (61440)   fp32 [b][h][1536], -1e30 pad
//   wv    370560   (3840000) fp32 attn out + bv
//   tbuf  4210560  (96000)
//   qh    4306560  (983040 f32 = 1966080 bf16)  [b][h][1536][32]
//   k1b   5289600  (49152 f32 = 98304 bf16)     [b][1536][32]
//   vhT   5338752  (1966080 f32 = 3932160 bf16) [b][h][64][1536]
//   end   7304832 floats = 29.2 MB
// ---------------------------------------------------------------------------

// K1: Wm[h,r,t] = 1/8 * sum_d Wq2[(h*64+d)*32+r] * Wk2[(h*64+d)*32+t]
//     b2s[h,t]  = 1/8 * sum_d bq[h*64+d] * Wk2[(h*64+d)*32+t]
__global__ void prep_wm_kernel(const float* __restrict__ Wq2, const float* __restrict__ Wk2,
                               const float* __restrict__ bq, float* __restrict__ wm,
                               float* __restrict__ b2s) {
  int h = blockIdx.x, tid = threadIdx.x;
  __shared__ float q2s[2048], k2s[2048], bqs[64];
  for (int e = tid; e < 2048; e += 256) {
    q2s[e] = Wq2[h * 2048 + e];
    k2s[e] = Wk2[h * 2048 + e];
  }
  if (tid < 64) bqs[tid] = bq[h * 64 + tid];
  __syncthreads();
  for (int e = tid; e < 1024; e += 256) {
    int r = e >> 5, t = e & 31;
    float s = 0.f;
    #pragma unroll 16
    for (int d = 0; d < 64; ++d) s += q2s[d * 32 + r] * k2s[d * 32 + t];
    wm[h * 1024 + r * 32 + t] = s * 0.125f;
  }
  if (tid < 32) {
    float s = 0.f;
    #pragma unroll 16
    for (int d = 0; d < 64; ++d) s += bqs[d] * k2s[d * 32 + tid];
    b2s[h * 32 + tid] = s * 0.125f;
  }
}

// K2: xp[row][0:32]=q1, [32:64]=k1, [64:96]=v1
__global__ void proj_qkv_kernel(const float* __restrict__ x, const float* __restrict__ Wq1,
                                const float* __restrict__ Wk1, const float* __restrict__ Wv1,
                                float* __restrict__ xp) {
  __shared__ __align__(16) float xs[8 * 1280];
  int tid = threadIdx.x;
  int rowbase = blockIdx.x * 8;
  const float4* xg = (const float4*)(x + (size_t)rowbase * 1280);
  float4* xs4 = (float4*)xs;
  for (int e = tid; e < 2560; e += 256) xs4[e] = xg[e];
  __syncthreads();
  int wave = tid >> 6, lane = tid & 63;
  for (int o = wave; o < 96; o += 4) {
    const float* wr = (o < 32) ? (Wq1 + o * 1280)
                               : ((o < 64) ? (Wk1 + (o - 32) * 1280) : (Wv1 + (o - 64) * 1280));
    const float4* w4 = (const float4*)wr;
    float acc[8];
    #pragma unroll
    for (int r = 0; r < 8; ++r) acc[r] = 0.f;
    #pragma unroll
    for (int it = 0; it < 5; ++it) {
      float4 w = w4[it * 64 + lane];
      #pragma unroll
      for (int r = 0; r < 8; ++r) {
        float4 xv = *(const float4*)&xs[r * 1280 + (it * 64 + lane) * 4];
        acc[r] += w.x * xv.x + w.y * xv.y + w.z * xv.z + w.w * xv.w;
      }
    }
    #pragma unroll
    for (int off = 32; off > 0; off >>= 1) {
      #pragma unroll
      for (int r = 0; r < 8; ++r) acc[r] += __shfl_down(acc[r], off, 64);
    }
    if (lane == 0) {
      #pragma unroll
      for (int r = 0; r < 8; ++r) xp[(size_t)(rowbase + r) * 96 + o] = acc[r];
    }
  }
}

// K3: qh bf16 [b][h][1536][32] = q1 @ wm[h]   (scale already folded into wm)
__global__ void prep_qh_kernel(const float* __restrict__ xp, const float* __restrict__ wm,
                               unsigned short* __restrict__ qhb) {
  int it = blockIdx.x, h = blockIdx.y, b = blockIdx.z;
  int i0 = it * 64, tid = threadIdx.x;
  __shared__ float q1s[2048];
  __shared__ float wms[1024];
  for (int e = tid; e < 2048; e += 256) {
    int row = e >> 5, r = e & 31;
    int i = i0 + row;
    q1s[e] = (i < Ss) ? xp[((size_t)b * Ss + i) * 96 + r] : 0.f;
  }
  for (int e = tid; e < 1024; e += 256) wms[e] = wm[h * 1024 + e];
  __syncthreads();
  int row = tid >> 2, tc = (tid & 3) * 8;
  float o[8];
  #pragma unroll
  for (int j = 0; j < 8; ++j) o[j] = 0.f;
  for (int r = 0; r < 32; ++r) {
    float qv = q1s[row * 32 + r];
    #pragma unroll
    for (int j = 0; j < 8; ++j) o[j] += qv * wms[r * 32 + tc + j];
  }
  short8 sv;
  #pragma unroll
  for (int j = 0; j < 8; ++j) sv[j] = (short)f2bf(o[j]);
  *(short8*)(qhb + ((size_t)(b * Hh + h) * SP + i0 + row) * 32 + tc) = sv;
}

// K4: k1b bf16 [b][1536][32]; kb fp32 [b][h][1536] (-1e30 pad); vhT bf16 [b][h][64][1536]
__global__ void prep_kv_kernel(const float* __restrict__ xp, const float* __restrict__ b2s,
                               const float* __restrict__ Wv2, unsigned short* __restrict__ k1b,
                               float* __restrict__ kbp, unsigned short* __restrict__ vhT) {
  int jt = blockIdx.x, h = blockIdx.y, b = blockIdx.z;
  int j0 = jt * 64, tid = threadIdx.x;
  __shared__ float k1s[2048], v1s[2048], wvs[2048];
  for (int e = tid; e < 2048; e += 256) {
    int row = e >> 5, r = e & 31;
    int j = j0 + row;
    float kv = 0.f, vv = 0.f;
    if (j < Ss) {
      const float* xr = xp + ((size_t)b * Ss + j) * 96;
      kv = xr[32 + r];
      vv = xr[64 + r];
    }
    k1s[e] = kv;
    v1s[e] = vv;
    wvs[e] = Wv2[h * 2048 + e];  // [d][r]
  }
  __syncthreads();
  if (h == 0) {
    for (int e = tid; e < 2048; e += 256)
      k1b[((size_t)b * SP + j0) * 32 + e] = f2bf(k1s[e]);
  }
  if (tid < 64) {
    int j = j0 + tid;
    float s = -1e30f;
    if (j < Ss) {
      s = 0.f;
      #pragma unroll 8
      for (int r = 0; r < 32; ++r) s += k1s[tid * 32 + r] * b2s[h * 32 + r];
    }
    kbp[(size_t)(b * Hh + h) * SP + j] = s;
  }
  int d = tid >> 2, jb = (tid & 3) * 16;
  float o[16];
  #pragma unroll
  for (int k = 0; k < 16; ++k) o[k] = 0.f;
  for (int r = 0; r < 32; ++r) {
    float wvv = wvs[d * 32 + r];
    #pragma unroll
    for (int k = 0; k < 16; ++k) o[k] += v1s[(jb + k) * 32 + r] * wvv;
  }
  unsigned short* vrow = vhT + ((size_t)(b * Hh + h) * 64 + d) * SP + j0 + jb;
  short8 s0, s1;
  #pragma unroll
  for (int k = 0; k < 8; ++k) { s0[k] = (short)f2bf(o[k]); s1[k] = (short)f2bf(o[8 + k]); }
  *(short8*)(vrow) = s0;
  *(short8*)(vrow + 8) = s1;
}

// K5: MFMA attention. 4 waves x 16 queries; Qh A-frag resident; double-buffered
// K/VhT staging via global_load_lds (pre-swizzled global source); per-wave P in LDS.
__global__ __launch_bounds__(256) void attn_mfma_kernel(
    const unsigned short* __restrict__ qhg, const unsigned short* __restrict__ k1g,
    const unsigned short* __restrict__ vhg, const float* __restrict__ kbg,
    const float* __restrict__ bv, float* __restrict__ wvp) {
  int it = blockIdx.x, h = blockIdx.y, b = blockIdx.z;
  int bh = b * Hh + h;
  int i0 = it * 64;
  int tid = threadIdx.x, w = tid >> 6, l = tid & 63;
  int l15 = l & 15, l4 = l >> 4;

  __shared__ short kS[2][2048];   // [buf][kgroup(4)][key(64)][8]
  __shared__ short vS[2][4096];   // [buf][d(64)][key(64)] 16B-slot-swizzled by d&7
  __shared__ float kbS[2][64];
  __shared__ short pS[4][1024];   // per-wave P [q(16)][key(64)] swizzled by q&7

  // resident Qh A-fragment: A[m=l15][k=l4*8+e]
  short8 qa = *(const short8*)(qhg + ((size_t)bh * SP + i0 + w * 16 + l15) * 32 + l4 * 8);
  VMW(0);  // drain qa so manual vmcnt counting below is exact

#define STAGE(bufi, tt)                                                                   \
  do {                                                                                    \
    int j0s = (tt) * 64;                                                                  \
    gload16(k1g + ((size_t)b * SP + j0s + l) * 32 + w * 8, &kS[bufi][w * 512]);           \
    int d0 = w * 16 + (l >> 3);                                                           \
    gload16(vhg + ((size_t)bh * 64 + d0) * SP + j0s + (((l & 7) ^ (d0 & 7)) << 3),        \
            &vS[bufi][w * 1024]);                                                         \
    int d1 = d0 + 8;                                                                      \
    gload16(vhg + ((size_t)bh * 64 + d1) * SP + j0s + (((l & 7) ^ (d1 & 7)) << 3),        \
            &vS[bufi][w * 1024 + 512]);                                                   \
    if (w == 0) gload4(kbg + (size_t)bh * SP + j0s + l, &kbS[bufi][0]);                   \
  } while (0)

  STAGE(0, 0);

  f32x4 acc[4];
  #pragma unroll
  for (int db = 0; db < 4; ++db) acc[db] = (f32x4){0.f, 0.f, 0.f, 0.f};
  float psr[4] = {0.f, 0.f, 0.f, 0.f};
  const f32x4 zf = (f32x4){0.f, 0.f, 0.f, 0.f};

  int cur = 0;
  for (int t = 0; t < NT; ++t) {
    if (t < NT - 1) {
      STAGE(cur ^ 1, t + 1);
      if (w == 0) VMW(4); else VMW(3);  // tile-t loads landed; t+1 stays in flight
    } else {
      VMW(0);
    }
    BAR();

    // ---- S = Qh @ K1^T, +kb, exp, pack to per-wave P_lds ----
    #pragma unroll
    for (int nb = 0; nb < 4; ++nb) {
      short8 kf = *(const short8*)&kS[cur][l4 * 512 + (nb * 16 + l15) * 8];
      f32x4 c = __builtin_amdgcn_mfma_f32_16x16x32_bf16(qa, kf, zf, 0, 0, 0);
      float kbv = kbS[cur][nb * 16 + l15];
      int slot_lo = nb * 2 + (l15 >> 3);
      #pragma unroll
      for (int reg = 0; reg < 4; ++reg) {
        int q = l4 * 4 + reg;
        float p = __expf(c[reg] + kbv);
        unsigned short us = f2bf(p);
        psr[reg] += __uint_as_float((unsigned)us << 16);  // sum exactly what PV sees
        pS[w][q * 64 + ((slot_lo ^ (q & 7)) << 3) + (l15 & 7)] = (short)us;
      }
    }

    // ---- O += P @ Vh ----
    #pragma unroll
    for (int kh = 0; kh < 2; ++kh) {
      short8 pa = *(const short8*)&pS[w][l15 * 64 + (((kh * 4 + l4) ^ (l15 & 7)) << 3)];
      #pragma unroll
      for (int db = 0; db < 4; ++db) {
        short8 vf =
            *(const short8*)&vS[cur][(db * 16 + l15) * 64 + (((kh * 4 + l4) ^ (l15 & 7)) << 3)];
        acc[db] = __builtin_amdgcn_mfma_f32_16x16x32_bf16(pa, vf, acc[db], 0, 0, 0);
      }
    }

    BAR();
    cur ^= 1;
  }
#undef STAGE

  // psum: reduce across the 16-lane key group (queries are per-(l4,reg))
  #pragma unroll
  for (int reg = 0; reg < 4; ++reg) {
    #pragma unroll
    for (int m = 1; m < 16; m <<= 1) psr[reg] += __shfl_xor(psr[reg], m, 64);
  }
  float inv[4];
  #pragma unroll
  for (int reg = 0; reg < 4; ++reg) inv[reg] = 1.f / psr[reg];

  #pragma unroll
  for (int db = 0; db < 4; ++db) {
    float bvv = bv[h * 64 + db * 16 + l15];
    #pragma unroll
    for (int reg = 0; reg < 4; ++reg) {
      int qi = i0 + w * 16 + l4 * 4 + reg;
      if (qi < Ss)
        wvp[((size_t)b * Ss + qi) * 1280 + h * 64 + db * 16 + l15] =
            acc[db][reg] * inv[reg] + bvv;
    }
  }
}

// K6a: tbuf[row][o] = sum_n wv[row][n] * Wo1[o][n]
__global__ void proj_o1_kernel(const float* __restrict__ wv, const float* __restrict__ Wo1,
                               float* __restrict__ tbuf) {
  __shared__ __align__(16) float xs[8 * 1280];
  int tid = threadIdx.x;
  int rowbase = blockIdx.x * 8;
  const float4* xg = (const float4*)(wv + (size_t)rowbase * 1280);
  float4* xs4 = (float4*)xs;
  for (int e = tid; e < 2560; e += 256) xs4[e] = xg[e];
  __syncthreads();
  int wave = tid >> 6, lane = tid & 63;
  for (int o = wave; o < 32; o += 4) {
    const float4* w4 = (const float4*)(Wo1 + o * 1280);
    float acc[8];
    #pragma unroll
    for (int r = 0; r < 8; ++r) acc[r] = 0.f;
    #pragma unroll
    for (int it = 0; it < 5; ++it) {
      float4 w = w4[it * 64 + lane];
      #pragma unroll
      for (int r = 0; r < 8; ++r) {
        float4 xv = *(const float4*)&xs[r * 1280 + (it * 64 + lane) * 4];
        acc[r] += w.x * xv.x + w.y * xv.y + w.z * xv.z + w.w * xv.w;
      }
    }
    #pragma unroll
    for (int off = 32; off > 0; off >>= 1) {
      #pragma unroll
      for (int r = 0; r < 8; ++r) acc[r] += __shfl_down(acc[r], off, 64);
    }
    if (lane == 0) {
      #pragma unroll
      for (int r = 0; r < 8; ++r) tbuf[(size_t)(rowbase + r) * 32 + o] = acc[r];
    }
  }
}

// K6b: out[row][n] = bo[n] + sum_o tbuf[row][o] * Wo2[n][o]
__global__ void proj_o2_kernel(const float* __restrict__ tbuf, const float* __restrict__ Wo2,
                               const float* __restrict__ bo, float* __restrict__ out) {
  int rb = blockIdx.x, nb = blockIdx.y, tid = threadIdx.x;
  int rowbase = rb * 16, n0 = nb * 256;
  __shared__ float ts[16 * 33];
  __shared__ float wos[256 * 33];
  for (int e = tid; e < 8192; e += 256) {
    int nloc = e >> 5, o = e & 31;
    wos[nloc * 33 + o] = Wo2[(size_t)(n0 + nloc) * 32 + o];
  }
  for (int e = tid; e < 512; e += 256) {
    int row = e >> 5, o = e & 31;
    int gr = rowbase + row;
    ts[row * 33 + o] = (gr < Bb * Ss) ? tbuf[(size_t)gr * 32 + o] : 0.f;
  }
  __syncthreads();
  int n = n0 + tid;
  float bias = bo[n];
  for (int row = 0; row < 16; ++row) {
    int gr = rowbase + row;
    if (gr >= Bb * Ss) break;
    float s = bias;
    #pragma unroll 8
    for (int o = 0; o < 32; ++o) s += ts[row * 33 + o] * wos[tid * 33 + o];
    out[(size_t)gr * 1280 + n] = s;
  }
}

extern "C" void kernel_launch(void* const* d_in, const int* in_sizes, int n_in,
                              void* d_out, int out_size, void* d_ws, size_t ws_size,
                              hipStream_t stream) {
  const float* x   = (const float*)d_in[0];
  const float* Wq1 = (const float*)d_in[1];
  const float* Wq2 = (const float*)d_in[2];
  const float* bq  = (const float*)d_in[3];
  const float* Wk1 = (const float*)d_in[4];
  const float* Wk2 = (const float*)d_in[5];
  // d_in[6] = bk : drops out of softmax (row-constant logit shift)
  const float* Wv1 = (const float*)d_in[7];
  const float* Wv2 = (const float*)d_in[8];
  const float* bv  = (const float*)d_in[9];
  const float* Wo1 = (const float*)d_in[10];
  const float* Wo2 = (const float*)d_in[11];
  const float* bo  = (const float*)d_in[12];
  float* out = (float*)d_out;
  float* ws  = (float*)d_ws;

  if (ws_size < (size_t)7304832 * sizeof(float)) return;

  float* wm   = ws;
  float* b2s  = ws + 20480;
  float* xp   = ws + 21120;
  float* kb   = ws + 309120;
  float* wv   = ws + 370560;
  float* tbuf = ws + 4210560;
  unsigned short* qhb = (unsigned short*)(ws + 4306560);
  unsigned short* k1b = (unsigned short*)(ws + 5289600);
  unsigned short* vhT = (unsigned short*)(ws + 5338752);

  prep_wm_kernel<<<20, 256, 0, stream>>>(Wq2, Wk2, bq, wm, b2s);
  proj_qkv_kernel<<<375, 256, 0, stream>>>(x, Wq1, Wk1, Wv1, xp);
  prep_qh_kernel<<<dim3(NT, Hh, Bb), 256, 0, stream>>>(xp, wm, qhb);
  prep_kv_kernel<<<dim3(NT, Hh, Bb), 256, 0, stream>>>(xp, b2s, Wv2, k1b, kb, vhT);
  attn_mfma_kernel<<<dim3(NT, Hh, Bb), 256, 0, stream>>>(qhb, k1b, vhT, kb, bv, wv);
  proj_o1_kernel<<<375, 256, 0, stream>>>(wv, Wo1, tbuf);
  proj_o2_kernel<<<dim3(188, 5), 256, 0, stream>>>(tbuf, Wo2, bo, out);
}

// Round 3
// 134.699 us; speedup vs baseline: 6.4594x; 2.2951x over previous
//
#include <hip/hip_runtime.h>
#include <math.h>

#define Bb 2
#define Ss 1500
#define SP 1536   // padded rows per batch (24 tiles of 64)
#define MR 3072   // total padded rows
#define Nn 1280
#define Hh 20
#define Rr 32
#define NT 24

typedef __attribute__((ext_vector_type(8))) short short8;
typedef __attribute__((ext_vector_type(4))) float f32x4;
typedef unsigned short ushort_t;

__device__ __forceinline__ unsigned short f2bf(float f) {
  unsigned u = __float_as_uint(f);
  u += 0x7fffu + ((u >> 16) & 1u);
  return (unsigned short)(u >> 16);
}
__device__ __forceinline__ float bf2f(unsigned short u) {
  return __uint_as_float((unsigned)u << 16);
}

__device__ __forceinline__ void gload16(const void* g, void* l) {
  __builtin_amdgcn_global_load_lds((const __attribute__((address_space(1))) unsigned int*)g,
                                   (__attribute__((address_space(3))) unsigned int*)l, 16, 0, 0);
}
__device__ __forceinline__ void gload4(const void* g, void* l) {
  __builtin_amdgcn_global_load_lds((const __attribute__((address_space(1))) unsigned int*)g,
                                   (__attribute__((address_space(3))) unsigned int*)l, 4, 0, 0);
}

#define BAR()                                  \
  do {                                         \
    asm volatile("" ::: "memory");             \
    __builtin_amdgcn_s_barrier();              \
    asm volatile("" ::: "memory");             \
  } while (0)

#define VMW(n) asm volatile("s_waitcnt vmcnt(" #n ")" ::: "memory")

// ---------------------------------------------------------------------------
// ws layout (float offsets):
//   wm     0        (20480)    fp32 Wq2h@Wk2h / 8
//   b2s    20480    (640)      fp32 bq@Wk2h / 8
//   xpq    21120    (96000)    fp32 q1 [3000][32]
//   kb     117120   (61440)    fp32 [40][1536], -1e30 pad
//   tbuf   178560   (96000)    fp32 [3000][32]
//   qhb    274560   (983040)   bf16 [40][1536][32]
//   k1b    1257600  (49152)    bf16 [2][1536][32]
//   v1b    1306752  (49152)    bf16 [2][32][1536]
//   xb     1355904  (1966080)  bf16 [3072][1280]
//   wcatb  3321984  (81920)    bf16 [128][1280] (q|k|v|0)
//   wo1b   3403904  (40960)    bf16 [64][1280]  (Wo1|0)
//   wv2b   3444864  (20480)    bf16 [1280][32]
//   wvb    3465344  (1966080)  bf16 [3072][1280]
//   end    5431424 floats = 21.7 MB
// ---------------------------------------------------------------------------

// cast x (fp32, [2][1500][1280]) -> xb bf16 [3072][1280], zero pad rows
__global__ void cast_x_kernel(const float* __restrict__ x, ushort_t* __restrict__ xb) {
  int gid = blockIdx.x * 256 + threadIdx.x;  // 491520 total (3072*160)
  int gr = gid / 160, c8 = gid % 160;
  int b = gr / SP, i = gr - b * SP;
  short8 v = (short8){0, 0, 0, 0, 0, 0, 0, 0};
  if (i < Ss) {
    const float* src = x + ((size_t)(b * Ss + i)) * 1280 + c8 * 8;
    float4 a0 = *(const float4*)src;
    float4 a1 = *(const float4*)(src + 4);
    v[0] = (short)f2bf(a0.x); v[1] = (short)f2bf(a0.y);
    v[2] = (short)f2bf(a0.z); v[3] = (short)f2bf(a0.w);
    v[4] = (short)f2bf(a1.x); v[5] = (short)f2bf(a1.y);
    v[6] = (short)f2bf(a1.z); v[7] = (short)f2bf(a1.w);
  }
  *(short8*)(xb + (size_t)gr * 1280 + c8 * 8) = v;
}

// cast weights to bf16: wcatb [128][1280] (Wq1|Wk1|Wv1|0), wo1b [64][1280] (Wo1|0),
// wv2b [1280][32]
__global__ void cast_w_kernel(const float* __restrict__ Wq1, const float* __restrict__ Wk1,
                              const float* __restrict__ Wv1, const float* __restrict__ Wo1,
                              const float* __restrict__ Wv2, ushort_t* __restrict__ wcatb,
                              ushort_t* __restrict__ wo1b, ushort_t* __restrict__ wv2b) {
  int gid = blockIdx.x * 256 + threadIdx.x;  // 35840
  const float* src = nullptr;
  ushort_t* dst = nullptr;
  if (gid < 20480) {
    int row = gid / 160, c8 = gid % 160;
    dst = wcatb + (size_t)row * 1280 + c8 * 8;
    if (row < 32) src = Wq1 + (size_t)row * 1280 + c8 * 8;
    else if (row < 64) src = Wk1 + (size_t)(row - 32) * 1280 + c8 * 8;
    else if (row < 96) src = Wv1 + (size_t)(row - 64) * 1280 + c8 * 8;
  } else if (gid < 30720) {
    int g = gid - 20480;
    int row = g / 160, c8 = g % 160;
    dst = wo1b + (size_t)row * 1280 + c8 * 8;
    if (row < 32) src = Wo1 + (size_t)row * 1280 + c8 * 8;
  } else {
    int g = gid - 30720;  // 5120: wv2b 1280 rows x 4 chunks
    int row = g >> 2, c8 = g & 3;
    dst = wv2b + row * 32 + c8 * 8;
    src = Wv2 + row * 32 + c8 * 8;
  }
  short8 v = (short8){0, 0, 0, 0, 0, 0, 0, 0};
  if (src) {
    #pragma unroll
    for (int j = 0; j < 8; ++j) v[j] = (short)f2bf(src[j]);
  }
  *(short8*)dst = v;
}

// Wm[h,r,t] = 1/8 * sum_d Wq2[(h*64+d)*32+r]*Wk2[(h*64+d)*32+t];  b2s likewise from bq
__global__ void prep_wm_kernel(const float* __restrict__ Wq2, const float* __restrict__ Wk2,
                               const float* __restrict__ bq, float* __restrict__ wm,
                               float* __restrict__ b2s) {
  int h = blockIdx.x, tid = threadIdx.x;
  __shared__ float q2s[2048], k2s[2048], bqs[64];
  for (int e = tid; e < 2048; e += 256) {
    q2s[e] = Wq2[h * 2048 + e];
    k2s[e] = Wk2[h * 2048 + e];
  }
  if (tid < 64) bqs[tid] = bq[h * 64 + tid];
  __syncthreads();
  for (int e = tid; e < 1024; e += 256) {
    int r = e >> 5, t = e & 31;
    float s = 0.f;
    #pragma unroll 16
    for (int d = 0; d < 64; ++d) s += q2s[d * 32 + r] * k2s[d * 32 + t];
    wm[h * 1024 + r * 32 + t] = s * 0.125f;
  }
  if (tid < 32) {
    float s = 0.f;
    #pragma unroll 16
    for (int d = 0; d < 64; ++d) s += bqs[d] * k2s[d * 32 + tid];
    b2s[h * 32 + tid] = s * 0.125f;
  }
}

// GEMM: [3072 x 1280] @ [96 x 1280]^T -> q1 fp32 / k1 bf16 / v1T bf16
// 64-row tiles, 4 waves (16 rows each), 6 N-frags, XOR-swizzled LDS tiles.
__global__ __launch_bounds__(256) void gemm_qkv_kernel(
    const ushort_t* __restrict__ xbg, const ushort_t* __restrict__ wcat,
    float* __restrict__ xpq, ushort_t* __restrict__ k1b, ushort_t* __restrict__ v1b) {
  int tid = threadIdx.x, w = tid >> 6, l = tid & 63, l15 = l & 15, l4 = l >> 4;
  int row0 = blockIdx.x * 64;
  __shared__ short As[2][2048];  // [64][32] swizzled
  __shared__ short Bs[2][4096];  // [128][32] swizzled
  int g8 = (((l & 3) ^ ((l >> 3) & 3)) << 3);  // pre-swizzled k-chunk (elems)
  const ushort_t* xsrc = xbg + (size_t)(row0 + w * 16 + (l >> 2)) * 1280 + g8;
  const ushort_t* w0src = wcat + (size_t)(w * 32 + (l >> 2)) * 1280 + g8;
  const ushort_t* w1src = wcat + (size_t)(w * 32 + 16 + (l >> 2)) * 1280 + g8;

#define QSTAGE(bufi, kk)                              \
  do {                                                \
    gload16(xsrc + (kk), &As[bufi][w * 512]);         \
    gload16(w0src + (kk), &Bs[bufi][w * 1024]);       \
    gload16(w1src + (kk), &Bs[bufi][w * 1024 + 512]); \
  } while (0)

  f32x4 acc[6];
  #pragma unroll
  for (int nf = 0; nf < 6; ++nf) acc[nf] = (f32x4){0.f, 0.f, 0.f, 0.f};

  QSTAGE(0, 0);
  int cur = 0;
  int aoff = (w * 16 + l15) * 32 + ((l4 ^ ((l15 >> 1) & 3)) << 3);
  int boff = l15 * 32 + ((l4 ^ ((l15 >> 1) & 3)) << 3);
  for (int t = 0; t < 40; ++t) {
    if (t < 39) {
      QSTAGE(cur ^ 1, (t + 1) * 32);
      VMW(3);
    } else {
      VMW(0);
    }
    BAR();
    short8 af = *(const short8*)&As[cur][aoff];
    #pragma unroll
    for (int nf = 0; nf < 6; ++nf) {
      short8 bf = *(const short8*)&Bs[cur][nf * 512 + boff];
      acc[nf] = __builtin_amdgcn_mfma_f32_16x16x32_bf16(af, bf, acc[nf], 0, 0, 0);
    }
    BAR();
    cur ^= 1;
  }
#undef QSTAGE

  #pragma unroll
  for (int nf = 0; nf < 6; ++nf) {
    int o = nf * 16 + l15;
    #pragma unroll
    for (int reg = 0; reg < 4; ++reg) {
      int gr = row0 + w * 16 + l4 * 4 + reg;
      int b = (gr >= SP) ? 1 : 0;
      int i = gr - b * SP;
      if (i < Ss) {
        float v = acc[nf][reg];
        if (o < 32) xpq[((size_t)b * Ss + i) * 32 + o] = v;
        else if (o < 64) k1b[((size_t)b * SP + i) * 32 + (o - 32)] = f2bf(v);
        else v1b[((size_t)b * 32 + (o - 64)) * SP + i] = f2bf(v);
      }
    }
  }
}

// GEMM: wvb [3072 x 1280] bf16 @ wo1b [64 x 1280]^T -> tbuf fp32 [3000][32]
__global__ __launch_bounds__(256) void gemm_o1_kernel(const ushort_t* __restrict__ wvg,
                                                      const ushort_t* __restrict__ wo1,
                                                      float* __restrict__ tbuf) {
  int tid = threadIdx.x, w = tid >> 6, l = tid & 63, l15 = l & 15, l4 = l >> 4;
  int row0 = blockIdx.x * 64;
  __shared__ short As[2][2048];  // [64][32]
  __shared__ short Bs[2][2048];  // [64][32]
  int g8 = (((l & 3) ^ ((l >> 3) & 3)) << 3);
  const ushort_t* xsrc = wvg + (size_t)(row0 + w * 16 + (l >> 2)) * 1280 + g8;
  const ushort_t* wsrc = wo1 + (size_t)(w * 16 + (l >> 2)) * 1280 + g8;

#define OSTAGE(bufi, kk)                      \
  do {                                        \
    gload16(xsrc + (kk), &As[bufi][w * 512]); \
    gload16(wsrc + (kk), &Bs[bufi][w * 512]); \
  } while (0)

  f32x4 acc[2];
  acc[0] = (f32x4){0.f, 0.f, 0.f, 0.f};
  acc[1] = (f32x4){0.f, 0.f, 0.f, 0.f};
  OSTAGE(0, 0);
  int cur = 0;
  int aoff = (w * 16 + l15) * 32 + ((l4 ^ ((l15 >> 1) & 3)) << 3);
  int boff = l15 * 32 + ((l4 ^ ((l15 >> 1) & 3)) << 3);
  for (int t = 0; t < 40; ++t) {
    if (t < 39) {
      OSTAGE(cur ^ 1, (t + 1) * 32);
      VMW(2);
    } else {
      VMW(0);
    }
    BAR();
    short8 af = *(const short8*)&As[cur][aoff];
    #pragma unroll
    for (int nf = 0; nf < 2; ++nf) {
      short8 bf = *(const short8*)&Bs[cur][nf * 512 + boff];
      acc[nf] = __builtin_amdgcn_mfma_f32_16x16x32_bf16(af, bf, acc[nf], 0, 0, 0);
    }
    BAR();
    cur ^= 1;
  }
#undef OSTAGE

  #pragma unroll
  for (int nf = 0; nf < 2; ++nf) {
    int o = nf * 16 + l15;
    #pragma unroll
    for (int reg = 0; reg < 4; ++reg) {
      int gr = row0 + w * 16 + l4 * 4 + reg;
      int b = (gr >= SP) ? 1 : 0;
      int i = gr - b * SP;
      if (i < Ss) tbuf[((size_t)b * Ss + i) * 32 + o] = acc[nf][reg];
    }
  }
}

// qhb bf16 [b,h][1536][32] = q1 @ wm[h]
__global__ void prep_qh_kernel(const float* __restrict__ xpq, const float* __restrict__ wm,
                               ushort_t* __restrict__ qhb) {
  int it = blockIdx.x, h = blockIdx.y, b = blockIdx.z;
  int i0 = it * 64, tid = threadIdx.x;
  __shared__ float q1s[64 * 33];
  __shared__ float wms[1024];
  for (int e = tid; e < 2048; e += 256) {
    int row = e >> 5, r = e & 31;
    int i = i0 + row;
    q1s[row * 33 + r] = (i < Ss) ? xpq[((size_t)b * Ss + i) * 32 + r] : 0.f;
  }
  for (int e = tid; e < 1024; e += 256) wms[e] = wm[h * 1024 + e];
  __syncthreads();
  int row = tid >> 2, tc = (tid & 3) * 8;
  float o[8];
  #pragma unroll
  for (int j = 0; j < 8; ++j) o[j] = 0.f;
  for (int r = 0; r < 32; ++r) {
    float qv = q1s[row * 33 + r];
    #pragma unroll
    for (int j = 0; j < 8; ++j) o[j] += qv * wms[r * 32 + tc + j];
  }
  short8 sv;
  #pragma unroll
  for (int j = 0; j < 8; ++j) sv[j] = (short)f2bf(o[j]);
  *(short8*)(qhb + ((size_t)(b * Hh + h) * SP + i0 + row) * 32 + tc) = sv;
}

// kb fp32 [b,h][1536] = k1 . b2s  (-1e30 pad)
__global__ void kb_kernel(const ushort_t* __restrict__ k1b, const float* __restrict__ b2s,
                          float* __restrict__ kbp) {
  int j0 = blockIdx.x * 64, b = blockIdx.y, tid = threadIdx.x;
  __shared__ float k1s[64 * 33];
  __shared__ float b2sh[20 * 33];
  for (int e = tid; e < 2048; e += 256) {
    int row = e >> 5, t = e & 31;
    k1s[row * 33 + t] = bf2f(k1b[((size_t)b * SP + j0 + row) * 32 + t]);
  }
  for (int e = tid; e < 640; e += 256) b2sh[(e >> 5) * 33 + (e & 31)] = b2s[e];
  __syncthreads();
  for (int e = tid; e < 1280; e += 256) {
    int h = e >> 6, rw = e & 63;
    int j = j0 + rw;
    float s = -1e30f;
    if (j < Ss) {
      s = 0.f;
      #pragma unroll 8
      for (int t = 0; t < 32; ++t) s += k1s[rw * 33 + t] * b2sh[h * 33 + t];
    }
    kbp[((size_t)b * Hh + h) * SP + j] = s;
  }
}

// Attention: per (i-tile, h, b). O = (P@v1)@Wv2h; no vh materialization.
__global__ __launch_bounds__(256) void attn2_kernel(
    const ushort_t* __restrict__ qhg, const ushort_t* __restrict__ k1g,
    const ushort_t* __restrict__ v1g, const ushort_t* __restrict__ wv2g,
    const float* __restrict__ kbg, const float* __restrict__ bv, ushort_t* __restrict__ wvb) {
  int it = blockIdx.x, h = blockIdx.y, b = blockIdx.z;
  int bh = b * Hh + h;
  int i0 = it * 64;
  int tid = threadIdx.x, w = tid >> 6, l = tid & 63;
  int l15 = l & 15, l4 = l >> 4;

  __shared__ short kS[2][2048];  // [kchunk(4)][key(64)][8]
  __shared__ short vS[2][2048];  // [r(32)][jslot(8)^swz][8]
  __shared__ float kbS[2][64];
  __shared__ short pS[4][1024];  // per-wave P [q(16)][key-slot swz][8]
  __shared__ short p2S[4][512];  // per-wave PV1 [q(16)][r-slot swz][8]

  // resident A-frag: Qh[q=l15][k=l4*8+e]
  short8 qa = *(const short8*)(qhg + ((size_t)bh * SP + i0 + w * 16 + l15) * 32 + l4 * 8);
  // resident B-frags: Wv2h[r=l4*8+e][d=db*16+l15]
  short8 wb0 = *(const short8*)(wv2g + (size_t)(h * 64 + 0 * 16 + l15) * 32 + l4 * 8);
  short8 wb1 = *(const short8*)(wv2g + (size_t)(h * 64 + 1 * 16 + l15) * 32 + l4 * 8);
  short8 wb2 = *(const short8*)(wv2g + (size_t)(h * 64 + 2 * 16 + l15) * 32 + l4 * 8);
  short8 wb3 = *(const short8*)(wv2g + (size_t)(h * 64 + 3 * 16 + l15) * 32 + l4 * 8);
  VMW(0);  // qa/wb landed; vmcnt counting below exact

  const ushort_t* ksrc = k1g + (size_t)b * SP * 32 + l * 32 + w * 8;
  const ushort_t* vsrc =
      v1g + ((size_t)b * 32 + w * 8 + (l >> 3)) * SP + (((l & 7) ^ ((l >> 3) & 7)) << 3);
  const float* kbsrc = kbg + (size_t)bh * SP + l;

#define STAGE(bufi, tt)                                   \
  do {                                                    \
    int j0s = (tt) * 64;                                  \
    gload16(ksrc + (size_t)j0s * 32, &kS[bufi][w * 512]); \
    gload16(vsrc + j0s, &vS[bufi][w * 512]);              \
    if (w == 0) gload4(kbsrc + j0s, &kbS[bufi][0]);       \
  } while (0)

  STAGE(0, 0);

  f32x4 acc[4];
  #pragma unroll
  for (int db = 0; db < 4; ++db) acc[db] = (f32x4){0.f, 0.f, 0.f, 0.f};
  float psr[4] = {0.f, 0.f, 0.f, 0.f};
  const f32x4 zf = (f32x4){0.f, 0.f, 0.f, 0.f};

  int cur = 0;
  for (int t = 0; t < NT; ++t) {
    if (t < NT - 1) {
      STAGE(cur ^ 1, t + 1);
      if (w == 0) VMW(3); else VMW(2);
    } else {
      VMW(0);
    }
    BAR();

    // S = Qh @ K1^T (+kb), exp, pack to per-wave P
    #pragma unroll
    for (int nb = 0; nb < 4; ++nb) {
      short8 kf = *(const short8*)&kS[cur][l4 * 512 + (nb * 16 + l15) * 8];
      f32x4 c = __builtin_amdgcn_mfma_f32_16x16x32_bf16(qa, kf, zf, 0, 0, 0);
      float kbv = kbS[cur][nb * 16 + l15];
      int slot_lo = nb * 2 + (l15 >> 3);
      #pragma unroll
      for (int reg = 0; reg < 4; ++reg) {
        int q = l4 * 4 + reg;
        float p = __expf(c[reg] + kbv);
        unsigned short us = f2bf(p);
        psr[reg] += __uint_as_float((unsigned)us << 16);
        pS[w][q * 64 + ((slot_lo ^ (q & 7)) << 3) + (l15 & 7)] = (short)us;
      }
    }

    // PV1 = P @ v1  (16q x 32r)
    f32x4 pv1[2];
    pv1[0] = (f32x4){0.f, 0.f, 0.f, 0.f};
    pv1[1] = (f32x4){0.f, 0.f, 0.f, 0.f};
    #pragma unroll
    for (int kh = 0; kh < 2; ++kh) {
      short8 pa = *(const short8*)&pS[w][l15 * 64 + (((kh * 4 + l4) ^ (l15 & 7)) << 3)];
      #pragma unroll
      for (int nf = 0; nf < 2; ++nf) {
        short8 vf =
            *(const short8*)&vS[cur][(nf * 16 + l15) * 64 + (((kh * 4 + l4) ^ (l15 & 7)) << 3)];
        pv1[nf] = __builtin_amdgcn_mfma_f32_16x16x32_bf16(pa, vf, pv1[nf], 0, 0, 0);
      }
    }

    // relayout PV1 -> A-frag via per-wave LDS (swizzled slots)
    #pragma unroll
    for (int nf = 0; nf < 2; ++nf) {
      #pragma unroll
      for (int reg = 0; reg < 4; ++reg) {
        int q = l4 * 4 + reg;
        int slot = nf * 2 + (l15 >> 3);
        p2S[w][q * 32 + ((slot ^ ((q >> 1) & 3)) << 3) + (l15 & 7)] =
            (short)f2bf(pv1[nf][reg]);
      }
    }
    short8 pa2 = *(const short8*)&p2S[w][l15 * 32 + ((l4 ^ ((l15 >> 1) & 3)) << 3)];

    // O += PV1 @ Wv2h
    acc[0] = __builtin_amdgcn_mfma_f32_16x16x32_bf16(pa2, wb0, acc[0], 0, 0, 0);
    acc[1] = __builtin_amdgcn_mfma_f32_16x16x32_bf16(pa2, wb1, acc[1], 0, 0, 0);
    acc[2] = __builtin_amdgcn_mfma_f32_16x16x32_bf16(pa2, wb2, acc[2], 0, 0, 0);
    acc[3] = __builtin_amdgcn_mfma_f32_16x16x32_bf16(pa2, wb3, acc[3], 0, 0, 0);

    BAR();
    cur ^= 1;
  }
#undef STAGE

  #pragma unroll
  for (int reg = 0; reg < 4; ++reg) {
    #pragma unroll
    for (int m = 1; m < 16; m <<= 1) psr[reg] += __shfl_xor(psr[reg], m, 64);
  }
  float inv[4];
  #pragma unroll
  for (int reg = 0; reg < 4; ++reg) inv[reg] = 1.f / psr[reg];

  #pragma unroll
  for (int db = 0; db < 4; ++db) {
    float bvv = bv[h * 64 + db * 16 + l15];
    #pragma unroll
    for (int reg = 0; reg < 4; ++reg) {
      int qi = i0 + w * 16 + l4 * 4 + reg;
      if (qi < Ss)
        wvb[((size_t)(b * SP + qi)) * 1280 + h * 64 + db * 16 + l15] =
            f2bf(acc[db][reg] * inv[reg] + bvv);
    }
  }
}

// out[row][n] = bo[n] + sum_o tbuf[row][o] * Wo2[n][o]
__global__ void proj_o2_kernel(const float* __restrict__ tbuf, const float* __restrict__ Wo2,
                               const float* __restrict__ bo, float* __restrict__ out) {
  int rb = blockIdx.x, nb = blockIdx.y, tid = threadIdx.x;
  int rowbase = rb * 16, n0 = nb * 256;
  __shared__ float ts[16 * 33];
  __shared__ float wos[256 * 33];
  for (int e = tid; e < 8192; e += 256) {
    int nloc = e >> 5, o = e & 31;
    wos[nloc * 33 + o] = Wo2[(size_t)(n0 + nloc) * 32 + o];
  }
  for (int e = tid; e < 512; e += 256) {
    int row = e >> 5, o = e & 31;
    int gr = rowbase + row;
    ts[row * 33 + o] = (gr < Bb * Ss) ? tbuf[(size_t)gr * 32 + o] : 0.f;
  }
  __syncthreads();
  int n = n0 + tid;
  float bias = bo[n];
  for (int row = 0; row < 16; ++row) {
    int gr = rowbase + row;
    if (gr >= Bb * Ss) break;
    float s = bias;
    #pragma unroll 8
    for (int o = 0; o < 32; ++o) s += ts[row * 33 + o] * wos[tid * 33 + o];
    out[(size_t)gr * 1280 + n] = s;
  }
}

extern "C" void kernel_launch(void* const* d_in, const int* in_sizes, int n_in,
                              void* d_out, int out_size, void* d_ws, size_t ws_size,
                              hipStream_t stream) {
  const float* x   = (const float*)d_in[0];
  const float* Wq1 = (const float*)d_in[1];
  const float* Wq2 = (const float*)d_in[2];
  const float* bq  = (const float*)d_in[3];
  const float* Wk1 = (const float*)d_in[4];
  const float* Wk2 = (const float*)d_in[5];
  // d_in[6] = bk : drops out of softmax (row-constant logit shift)
  const float* Wv1 = (const float*)d_in[7];
  const float* Wv2 = (const float*)d_in[8];
  const float* bv  = (const float*)d_in[9];
  const float* Wo1 = (const float*)d_in[10];
  const float* Wo2 = (const float*)d_in[11];
  const float* bo  = (const float*)d_in[12];
  float* out = (float*)d_out;
  float* ws  = (float*)d_ws;

  if (ws_size < (size_t)5431424 * sizeof(float)) return;

  float* wm    = ws;
  float* b2s   = ws + 20480;
  float* xpq   = ws + 21120;
  float* kb    = ws + 117120;
  float* tbuf  = ws + 178560;
  ushort_t* qhb   = (ushort_t*)(ws + 274560);
  ushort_t* k1b   = (ushort_t*)(ws + 1257600);
  ushort_t* v1b   = (ushort_t*)(ws + 1306752);
  ushort_t* xb    = (ushort_t*)(ws + 1355904);
  ushort_t* wcatb = (ushort_t*)(ws + 3321984);
  ushort_t* wo1b  = (ushort_t*)(ws + 3403904);
  ushort_t* wv2b  = (ushort_t*)(ws + 3444864);
  ushort_t* wvb   = (ushort_t*)(ws + 3465344);

  cast_x_kernel<<<1920, 256, 0, stream>>>(x, xb);
  cast_w_kernel<<<140, 256, 0, stream>>>(Wq1, Wk1, Wv1, Wo1, Wv2, wcatb, wo1b, wv2b);
  prep_wm_kernel<<<20, 256, 0, stream>>>(Wq2, Wk2, bq, wm, b2s);
  gemm_qkv_kernel<<<48, 256, 0, stream>>>(xb, wcatb, xpq, k1b, v1b);
  prep_qh_kernel<<<dim3(NT, Hh, Bb), 256, 0, stream>>>(xpq, wm, qhb);
  kb_kernel<<<dim3(NT, Bb), 256, 0, stream>>>(k1b, b2s, kb);
  attn2_kernel<<<dim3(NT, Hh, Bb), 256, 0, stream>>>(qhb, k1b, v1b, wv2b, kb, bv, wvb);
  gemm_o1_kernel<<<48, 256, 0, stream>>>(wvb, wo1b, tbuf);
  proj_o2_kernel<<<dim3(188, 5), 256, 0, stream>>>(tbuf, Wo2, bo, out);
}

// Round 4
// 121.384 us; speedup vs baseline: 7.1679x; 1.1097x over previous
//
#include <hip/hip_runtime.h>
#include <math.h>

#define Bb 2
#define Ss 1500
#define SP 1536   // padded rows per batch (24 tiles of 64)
#define Nn 1280
#define Hh 20
#define Rr 32
#define NT 24     // key tiles of 64
#define NI 48     // query tiles of 32

typedef __attribute__((ext_vector_type(8))) short short8;
typedef __attribute__((ext_vector_type(4))) float f32x4;
typedef unsigned short ushort_t;

__device__ __forceinline__ unsigned short f2bf(float f) {
  unsigned u = __float_as_uint(f);
  u += 0x7fffu + ((u >> 16) & 1u);
  return (unsigned short)(u >> 16);
}
__device__ __forceinline__ float bf2f(unsigned short u) {
  return __uint_as_float((unsigned)u << 16);
}
__device__ __forceinline__ unsigned cvtpk(float a, float b) {
  unsigned d;
  asm("v_cvt_pk_bf16_f32 %0, %1, %2" : "=v"(d) : "v"(a), "v"(b));
  return d;  // lo16 = bf16(a), hi16 = bf16(b), RNE
}

__device__ __forceinline__ void gload16(const void* g, void* l) {
  __builtin_amdgcn_global_load_lds((const __attribute__((address_space(1))) unsigned int*)g,
                                   (__attribute__((address_space(3))) unsigned int*)l, 16, 0, 0);
}
__device__ __forceinline__ void gload4(const void* g, void* l) {
  __builtin_amdgcn_global_load_lds((const __attribute__((address_space(1))) unsigned int*)g,
                                   (__attribute__((address_space(3))) unsigned int*)l, 4, 0, 0);
}

#define BAR()                                  \
  do {                                         \
    asm volatile("" ::: "memory");             \
    __builtin_amdgcn_s_barrier();              \
    asm volatile("" ::: "memory");             \
  } while (0)

#define VMW(n) asm volatile("s_waitcnt vmcnt(" #n ")" ::: "memory")

// ---------------------------------------------------------------------------
// ws layout (float offsets):
//   wm     0        (20480)    fp32 Wq2h@Wk2h / 8
//   b2s    20480    (640)      fp32 bq@Wk2h / 8
//   xpq    21120    (96000)    fp32 q1 [3000][32]
//   kb     117120   (61440)    fp32 [40][1536], -1e30 pad
//   tbuf   178560   (96000)    fp32 [3000][32]
//   qhb    274560   (983040)   bf16 [40][1536][32]
//   k1b    1257600  (49152)    bf16 [2][1536][32]
//   v1b    1306752  (49152)    bf16 [2][32][1536]
//   xb     1355904  (1966080)  bf16 [3072][1280]
//   wcatb  3321984  (81920)    bf16 [128][1280] (q|k|v|0)
//   wo1b   3403904  (40960)    bf16 [64][1280]  (Wo1|0)
//   wv2b   3444864  (20480)    bf16 [1280][32]
//   wvb    3465344  (1966080)  bf16 [3072][1280]
//   end    5431424 floats = 21.7 MB
// ---------------------------------------------------------------------------

// merged prep: blocks [0,1920): cast x; [1920,2060): cast weights; [2060,2080): wm/b2s
__global__ void prep_kernel(const float* __restrict__ x, const float* __restrict__ Wq1,
                            const float* __restrict__ Wk1, const float* __restrict__ Wv1,
                            const float* __restrict__ Wo1, const float* __restrict__ Wq2,
                            const float* __restrict__ Wk2, const float* __restrict__ Wv2,
                            const float* __restrict__ bq, ushort_t* __restrict__ xb,
                            ushort_t* __restrict__ wcatb, ushort_t* __restrict__ wo1b,
                            ushort_t* __restrict__ wv2b, float* __restrict__ wm,
                            float* __restrict__ b2s) {
  int bid = blockIdx.x, tid = threadIdx.x;
  __shared__ float q2s[2048], k2s[2048], bqs[64];
  if (bid < 1920) {
    int gid = bid * 256 + tid;  // 491520 = 3072*160
    int gr = gid / 160, c8 = gid % 160;
    int b = gr / SP, i = gr - b * SP;
    short8 v = (short8){0, 0, 0, 0, 0, 0, 0, 0};
    if (i < Ss) {
      const float* src = x + ((size_t)(b * Ss + i)) * 1280 + c8 * 8;
      float4 a0 = *(const float4*)src;
      float4 a1 = *(const float4*)(src + 4);
      v[0] = (short)f2bf(a0.x); v[1] = (short)f2bf(a0.y);
      v[2] = (short)f2bf(a0.z); v[3] = (short)f2bf(a0.w);
      v[4] = (short)f2bf(a1.x); v[5] = (short)f2bf(a1.y);
      v[6] = (short)f2bf(a1.z); v[7] = (short)f2bf(a1.w);
    }
    *(short8*)(xb + (size_t)gr * 1280 + c8 * 8) = v;
  } else if (bid < 2060) {
    int gid = (bid - 1920) * 256 + tid;  // 35840
    const float* src = nullptr;
    ushort_t* dst = nullptr;
    if (gid < 20480) {
      int row = gid / 160, c8 = gid % 160;
      dst = wcatb + (size_t)row * 1280 + c8 * 8;
      if (row < 32) src = Wq1 + (size_t)row * 1280 + c8 * 8;
      else if (row < 64) src = Wk1 + (size_t)(row - 32) * 1280 + c8 * 8;
      else if (row < 96) src = Wv1 + (size_t)(row - 64) * 1280 + c8 * 8;
    } else if (gid < 30720) {
      int g = gid - 20480;
      int row = g / 160, c8 = g % 160;
      dst = wo1b + (size_t)row * 1280 + c8 * 8;
      if (row < 32) src = Wo1 + (size_t)row * 1280 + c8 * 8;
    } else {
      int g = gid - 30720;
      int row = g >> 2, c8 = g & 3;
      dst = wv2b + row * 32 + c8 * 8;
      src = Wv2 + row * 32 + c8 * 8;
    }
    short8 v = (short8){0, 0, 0, 0, 0, 0, 0, 0};
    if (src) {
      #pragma unroll
      for (int j = 0; j < 8; ++j) v[j] = (short)f2bf(src[j]);
    }
    *(short8*)dst = v;
  } else {
    int h = bid - 2060;
    for (int e = tid; e < 2048; e += 256) {
      q2s[e] = Wq2[h * 2048 + e];
      k2s[e] = Wk2[h * 2048 + e];
    }
    if (tid < 64) bqs[tid] = bq[h * 64 + tid];
    __syncthreads();
    for (int e = tid; e < 1024; e += 256) {
      int r = e >> 5, t = e & 31;
      float s = 0.f;
      #pragma unroll 16
      for (int d = 0; d < 64; ++d) s += q2s[d * 32 + r] * k2s[d * 32 + t];
      wm[h * 1024 + r * 32 + t] = s * 0.125f;
    }
    if (tid < 32) {
      float s = 0.f;
      #pragma unroll 16
      for (int d = 0; d < 64; ++d) s += bqs[d] * k2s[d * 32 + tid];
      b2s[h * 32 + tid] = s * 0.125f;
    }
  }
}

// GEMM: xb[3072x1280]bf16 @ wcat[96x1280]^T -> q1 fp32 / k1 bf16 / v1T bf16
// rowtile 32, 2 waves x 16 rows x 6 frags, BK=64, XOR-swizzled LDS.
__global__ __launch_bounds__(128) void gemm_qkv_kernel(
    const ushort_t* __restrict__ xbg, const ushort_t* __restrict__ wcat,
    float* __restrict__ xpq, ushort_t* __restrict__ k1b, ushort_t* __restrict__ v1b) {
  int tid = threadIdx.x, w = tid >> 6, l = tid & 63, l15 = l & 15, l4 = l >> 4;
  int row0 = blockIdx.x * 32;
  __shared__ __align__(16) short As[2][2048];  // [32][64] swz
  __shared__ __align__(16) short Bs[2][6144];  // [96][64] swz
  int sw8 = (((l & 7) ^ ((l >> 3) & 7)) << 3);  // pre-swizzled chunk for staging
  const ushort_t* asrc0 = xbg + (size_t)(row0 + w * 16 + (l >> 3)) * 1280 + sw8;
  const ushort_t* asrc1 = asrc0 + (size_t)8 * 1280;
  const ushort_t* bsrc[6];
  #pragma unroll
  for (int g = 0; g < 6; ++g)
    bsrc[g] = wcat + (size_t)(w * 48 + g * 8 + (l >> 3)) * 1280 + sw8;

#define QSTAGE(bufi, kk)                                            \
  do {                                                              \
    gload16(asrc0 + (kk), &As[bufi][w * 1024]);                     \
    gload16(asrc1 + (kk), &As[bufi][w * 1024 + 512]);               \
    gload16(bsrc[0] + (kk), &Bs[bufi][w * 3072]);                   \
    gload16(bsrc[1] + (kk), &Bs[bufi][w * 3072 + 512]);             \
    gload16(bsrc[2] + (kk), &Bs[bufi][w * 3072 + 1024]);            \
    gload16(bsrc[3] + (kk), &Bs[bufi][w * 3072 + 1536]);            \
    gload16(bsrc[4] + (kk), &Bs[bufi][w * 3072 + 2048]);            \
    gload16(bsrc[5] + (kk), &Bs[bufi][w * 3072 + 2560]);            \
  } while (0)

  f32x4 acc[6];
  #pragma unroll
  for (int nf = 0; nf < 6; ++nf) acc[nf] = (f32x4){0.f, 0.f, 0.f, 0.f};

  QSTAGE(0, 0);
  int cur = 0;
  for (int t = 0; t < 20; ++t) {
    if (t < 19) {
      QSTAGE(cur ^ 1, (t + 1) * 64);
      VMW(8);
    } else {
      VMW(0);
    }
    BAR();
    #pragma unroll
    for (int ks = 0; ks < 2; ++ks) {
      short8 af = *(const short8*)&As[cur][(w * 16 + l15) * 64 +
                                           (((ks * 4 + l4) ^ (l15 & 7)) << 3)];
      #pragma unroll
      for (int nf = 0; nf < 6; ++nf) {
        short8 bf = *(const short8*)&Bs[cur][(nf * 16 + l15) * 64 +
                                             (((ks * 4 + l4) ^ (l15 & 7)) << 3)];
        acc[nf] = __builtin_amdgcn_mfma_f32_16x16x32_bf16(af, bf, acc[nf], 0, 0, 0);
      }
    }
    BAR();
    cur ^= 1;
  }
#undef QSTAGE

  #pragma unroll
  for (int nf = 0; nf < 6; ++nf) {
    int o = nf * 16 + l15;
    #pragma unroll
    for (int reg = 0; reg < 4; ++reg) {
      int gr = row0 + w * 16 + l4 * 4 + reg;
      int b = (gr >= SP) ? 1 : 0;
      int i = gr - b * SP;
      if (i < Ss) {
        float v = acc[nf][reg];
        if (o < 32) xpq[((size_t)b * Ss + i) * 32 + o] = v;
        else if (o < 64) k1b[((size_t)b * SP + i) * 32 + (o - 32)] = f2bf(v);
        else v1b[((size_t)b * 32 + (o - 64)) * SP + i] = f2bf(v);
      }
    }
  }
}

// merged: blockIdx.y<20 -> qh (per i-tile,h,b); blockIdx.y==20 -> kb (per j-tile,b)
__global__ void qh_kb_kernel(const float* __restrict__ xpq, const float* __restrict__ wm,
                             const float* __restrict__ b2s, const ushort_t* __restrict__ k1b,
                             ushort_t* __restrict__ qhb, float* __restrict__ kbp) {
  int tid = threadIdx.x, b = blockIdx.z;
  if (blockIdx.y == 20) {
    int j0 = blockIdx.x * 64;
    __shared__ float k1s[64 * 33];
    __shared__ float b2sh[20 * 33];
    for (int e = tid; e < 2048; e += 256) {
      int row = e >> 5, t = e & 31;
      k1s[row * 33 + t] = bf2f(k1b[((size_t)b * SP + j0 + row) * 32 + t]);
    }
    for (int e = tid; e < 640; e += 256) b2sh[(e >> 5) * 33 + (e & 31)] = b2s[e];
    __syncthreads();
    for (int e = tid; e < 1280; e += 256) {
      int h = e >> 6, rw = e & 63;
      int j = j0 + rw;
      float s = -1e30f;
      if (j < Ss) {
        s = 0.f;
        #pragma unroll 8
        for (int t = 0; t < 32; ++t) s += k1s[rw * 33 + t] * b2sh[h * 33 + t];
      }
      kbp[((size_t)b * Hh + h) * SP + j] = s;
    }
  } else {
    int it = blockIdx.x, h = blockIdx.y;
    int i0 = it * 64;
    __shared__ float q1s[64 * 33];
    __shared__ float wms[1024];
    for (int e = tid; e < 2048; e += 256) {
      int row = e >> 5, r = e & 31;
      int i = i0 + row;
      q1s[row * 33 + r] = (i < Ss) ? xpq[((size_t)b * Ss + i) * 32 + r] : 0.f;
    }
    for (int e = tid; e < 1024; e += 256) wms[e] = wm[h * 1024 + e];
    __syncthreads();
    int row = tid >> 2, tc = (tid & 3) * 8;
    float o[8];
    #pragma unroll
    for (int j = 0; j < 8; ++j) o[j] = 0.f;
    for (int r = 0; r < 32; ++r) {
      float qv = q1s[row * 33 + r];
      #pragma unroll
      for (int j = 0; j < 8; ++j) o[j] += qv * wms[r * 32 + tc + j];
    }
    short8 sv;
    #pragma unroll
    for (int j = 0; j < 8; ++j) sv[j] = (short)f2bf(o[j]);
    *(short8*)(qhb + ((size_t)(b * Hh + h) * SP + i0 + row) * 32 + tc) = sv;
  }
}

// Attention v2: swapped-operand MFMAs so lanes hold key/r-consecutive values;
// cvt_pk + b64 LDS writes; 2 waves x 16 queries; 1920 blocks.
__global__ __launch_bounds__(128) void attn2_kernel(
    const ushort_t* __restrict__ qhg, const ushort_t* __restrict__ k1g,
    const ushort_t* __restrict__ v1g, const ushort_t* __restrict__ wv2g,
    const float* __restrict__ kbg, const float* __restrict__ bv, ushort_t* __restrict__ wvb) {
  int it = blockIdx.x, h = blockIdx.y, b = blockIdx.z;
  int bh = b * Hh + h;
  int i0 = it * 32;
  int tid = threadIdx.x, w = tid >> 6, l = tid & 63;
  int l15 = l & 15, l4 = l >> 4;

  __shared__ __align__(16) short kS[2][2048];   // [chunk(4)][key(64)][8]
  __shared__ __align__(16) short vS[2][2048];   // [r(32)][key slots swz]
  __shared__ __align__(16) float kbS[2][64];
  __shared__ __align__(16) short pS[2][1024];   // per-wave P [q(16)][key slots swz]
  __shared__ __align__(16) short p2S[2][512];   // per-wave PV1 [q(16)][r slots swz]

  // resident B-frags: Qh[n=q=l15][k=l4*8+e], Wv2h[n=d][k=r]
  short8 qa = *(const short8*)(qhg + ((size_t)bh * SP + i0 + w * 16 + l15) * 32 + l4 * 8);
  short8 wb0 = *(const short8*)(wv2g + (size_t)(h * 64 + 0 * 16 + l15) * 32 + l4 * 8);
  short8 wb1 = *(const short8*)(wv2g + (size_t)(h * 64 + 1 * 16 + l15) * 32 + l4 * 8);
  short8 wb2 = *(const short8*)(wv2g + (size_t)(h * 64 + 2 * 16 + l15) * 32 + l4 * 8);
  short8 wb3 = *(const short8*)(wv2g + (size_t)(h * 64 + 3 * 16 + l15) * 32 + l4 * 8);
  VMW(0);  // drain residents so vmcnt counting is exact

  const ushort_t* ksrc = k1g + (size_t)b * SP * 32 + l * 32 + w * 16;  // chunks 2w,2w+1
  int r0 = w * 16 + (l >> 3);
  const ushort_t* vsrc0 = v1g + ((size_t)b * 32 + r0) * SP + (((l & 7) ^ (r0 & 7)) << 3);
  int r1 = r0 + 8;
  const ushort_t* vsrc1 = v1g + ((size_t)b * 32 + r1) * SP + (((l & 7) ^ (r1 & 7)) << 3);
  const float* kbsrc = kbg + (size_t)bh * SP + l;

#define STAGE(bufi, tt)                                              \
  do {                                                               \
    int j0s = (tt) * 64;                                             \
    gload16(ksrc + (size_t)j0s * 32, &kS[bufi][w * 1024]);           \
    gload16(ksrc + (size_t)j0s * 32 + 8, &kS[bufi][w * 1024 + 512]); \
    gload16(vsrc0 + j0s, &vS[bufi][w * 1024]);                       \
    gload16(vsrc1 + j0s, &vS[bufi][w * 1024 + 512]);                 \
    if (w == 0) gload4(kbsrc + j0s, &kbS[bufi][0]);                  \
  } while (0)

  STAGE(0, 0);

  f32x4 acc[4];
  #pragma unroll
  for (int db = 0; db < 4; ++db) acc[db] = (f32x4){0.f, 0.f, 0.f, 0.f};
  float psum = 0.f;
  const f32x4 zf = (f32x4){0.f, 0.f, 0.f, 0.f};

  int cur = 0;
  for (int t = 0; t < NT; ++t) {
    if (t < NT - 1) {
      STAGE(cur ^ 1, t + 1);
      if (w == 0) VMW(5); else VMW(4);
    } else {
      VMW(0);
    }
    BAR();

    // S^T = K1 @ Qh^T: lane holds keys nb*16+l4*4+reg for query l15
    #pragma unroll
    for (int nb = 0; nb < 4; ++nb) {
      short8 kf = *(const short8*)&kS[cur][l4 * 512 + (nb * 16 + l15) * 8];
      f32x4 c = __builtin_amdgcn_mfma_f32_16x16x32_bf16(kf, qa, zf, 0, 0, 0);
      float4 kbv = *(const float4*)&kbS[cur][nb * 16 + l4 * 4];
      float p0 = __expf(c[0] + kbv.x);
      float p1 = __expf(c[1] + kbv.y);
      float p2 = __expf(c[2] + kbv.z);
      float p3 = __expf(c[3] + kbv.w);
      psum += (p0 + p1) + (p2 + p3);
      uint2 pk;
      pk.x = cvtpk(p0, p1);
      pk.y = cvtpk(p2, p3);
      *(uint2*)&pS[w][l15 * 64 + (((nb * 4 + l4) ^ ((l15 & 7) << 1)) << 2)] = pk;
    }

    // PV1^T = v1 @ P^T: lane holds r = nf*16+l4*4+reg for query l15
    f32x4 pv1[2];
    pv1[0] = zf;
    pv1[1] = zf;
    #pragma unroll
    for (int kh = 0; kh < 2; ++kh) {
      short8 pa = *(const short8*)&pS[w][l15 * 64 +
                                         (((kh * 8 + 2 * l4) ^ ((l15 & 7) << 1)) << 2)];
      #pragma unroll
      for (int nf = 0; nf < 2; ++nf) {
        short8 vf = *(const short8*)&vS[cur][(nf * 16 + l15) * 64 +
                                             (((kh * 4 + l4) ^ (l15 & 7)) << 3)];
        pv1[nf] = __builtin_amdgcn_mfma_f32_16x16x32_bf16(vf, pa, pv1[nf], 0, 0, 0);
      }
    }

    // pack PV1 -> A-frag rows (b64 writes), then O += PV1 @ Wv2h
    #pragma unroll
    for (int nf = 0; nf < 2; ++nf) {
      uint2 pk;
      pk.x = cvtpk(pv1[nf][0], pv1[nf][1]);
      pk.y = cvtpk(pv1[nf][2], pv1[nf][3]);
      *(uint2*)&p2S[w][l15 * 32 + (((nf * 4 + l4) ^ (l15 & 6)) << 2)] = pk;
    }
    short8 pa2 = *(const short8*)&p2S[w][l15 * 32 + (((2 * l4) ^ (l15 & 6)) << 2)];
    acc[0] = __builtin_amdgcn_mfma_f32_16x16x32_bf16(pa2, wb0, acc[0], 0, 0, 0);
    acc[1] = __builtin_amdgcn_mfma_f32_16x16x32_bf16(pa2, wb1, acc[1], 0, 0, 0);
    acc[2] = __builtin_amdgcn_mfma_f32_16x16x32_bf16(pa2, wb2, acc[2], 0, 0, 0);
    acc[3] = __builtin_amdgcn_mfma_f32_16x16x32_bf16(pa2, wb3, acc[3], 0, 0, 0);

    BAR();
    cur ^= 1;
  }
#undef STAGE

  // psum: lane has partial for query l15 -> reduce over the 4 l4-groups
  psum += __shfl_xor(psum, 16, 64);
  psum += __shfl_xor(psum, 32, 64);
  float invq[4];
  #pragma unroll
  for (int reg = 0; reg < 4; ++reg) invq[reg] = 1.f / __shfl(psum, l4 * 4 + reg, 64);

  #pragma unroll
  for (int db = 0; db < 4; ++db) {
    float bvv = bv[h * 64 + db * 16 + l15];
    #pragma unroll
    for (int reg = 0; reg < 4; ++reg) {
      int qi = i0 + w * 16 + l4 * 4 + reg;
      if (qi < Ss)
        wvb[((size_t)(b * SP + qi)) * 1280 + h * 64 + db * 16 + l15] =
            f2bf(acc[db][reg] * invq[reg] + bvv);
    }
  }
}

// GEMM: wvb[3072x1280]bf16 @ wo1b[32x1280]^T -> tbuf fp32, rowtile 32, BK=64
__global__ __launch_bounds__(128) void gemm_o1_kernel(const ushort_t* __restrict__ wvg,
                                                      const ushort_t* __restrict__ wo1,
                                                      float* __restrict__ tbuf) {
  int tid = threadIdx.x, w = tid >> 6, l = tid & 63, l15 = l & 15, l4 = l >> 4;
  int row0 = blockIdx.x * 32;
  __shared__ __align__(16) short As[2][2048];  // [32][64]
  __shared__ __align__(16) short Bs[2][2048];  // [32][64]
  int sw8 = (((l & 7) ^ ((l >> 3) & 7)) << 3);
  const ushort_t* asrc0 = wvg + (size_t)(row0 + w * 16 + (l >> 3)) * 1280 + sw8;
  const ushort_t* asrc1 = asrc0 + (size_t)8 * 1280;
  const ushort_t* bsrc = wo1 + (size_t)(w * 16 + (l >> 3)) * 1280 + sw8;
  const ushort_t* bsrc1 = bsrc + (size_t)8 * 1280;

#define OSTAGE(bufi, kk)                                 \
  do {                                                   \
    gload16(asrc0 + (kk), &As[bufi][w * 1024]);          \
    gload16(asrc1 + (kk), &As[bufi][w * 1024 + 512]);    \
    gload16(bsrc + (kk), &Bs[bufi][w * 1024]);           \
    gload16(bsrc1 + (kk), &Bs[bufi][w * 1024 + 512]);    \
  } while (0)

  f32x4 acc[2];
  acc[0] = (f32x4){0.f, 0.f, 0.f, 0.f};
  acc[1] = (f32x4){0.f, 0.f, 0.f, 0.f};
  OSTAGE(0, 0);
  int cur = 0;
  for (int t = 0; t < 20; ++t) {
    if (t < 19) {
      OSTAGE(cur ^ 1, (t + 1) * 64);
      VMW(4);
    } else {
      VMW(0);
    }
    BAR();
    #pragma unroll
    for (int ks = 0; ks < 2; ++ks) {
      short8 af = *(const short8*)&As[cur][(w * 16 + l15) * 64 +
                                           (((ks * 4 + l4) ^ (l15 & 7)) << 3)];
      #pragma unroll
      for (int nf = 0; nf < 2; ++nf) {
        short8 bf = *(const short8*)&Bs[cur][(nf * 16 + l15) * 64 +
                                             (((ks * 4 + l4) ^ (l15 & 7)) << 3)];
        acc[nf] = __builtin_amdgcn_mfma_f32_16x16x32_bf16(af, bf, acc[nf], 0, 0, 0);
      }
    }
    BAR();
    cur ^= 1;
  }
#undef OSTAGE

  #pragma unroll
  for (int nf = 0; nf < 2; ++nf) {
    int o = nf * 16 + l15;
    #pragma unroll
    for (int reg = 0; reg < 4; ++reg) {
      int gr = row0 + w * 16 + l4 * 4 + reg;
      int b = (gr >= SP) ? 1 : 0;
      int i = gr - b * SP;
      if (i < Ss) tbuf[((size_t)b * Ss + i) * 32 + o] = acc[nf][reg];
    }
  }
}

// out[row][n] = bo[n] + sum_o tbuf[row][o] * Wo2[n][o]
__global__ void proj_o2_kernel(const float* __restrict__ tbuf, const float* __restrict__ Wo2,
                               const float* __restrict__ bo, float* __restrict__ out) {
  int rb = blockIdx.x, nb = blockIdx.y, tid = threadIdx.x;
  int rowbase = rb * 16, n0 = nb * 256;
  __shared__ float ts[16 * 33];
  __shared__ float wos[256 * 33];
  for (int e = tid; e < 8192; e += 256) {
    int nloc = e >> 5, o = e & 31;
    wos[nloc * 33 + o] = Wo2[(size_t)(n0 + nloc) * 32 + o];
  }
  for (int e = tid; e < 512; e += 256) {
    int row = e >> 5, o = e & 31;
    int gr = rowbase + row;
    ts[row * 33 + o] = (gr < Bb * Ss) ? tbuf[(size_t)gr * 32 + o] : 0.f;
  }
  __syncthreads();
  int n = n0 + tid;
  float bias = bo[n];
  for (int row = 0; row < 16; ++row) {
    int gr = rowbase + row;
    if (gr >= Bb * Ss) break;
    float s = bias;
    #pragma unroll 8
    for (int o = 0; o < 32; ++o) s += ts[row * 33 + o] * wos[tid * 33 + o];
    out[(size_t)gr * 1280 + n] = s;
  }
}

extern "C" void kernel_launch(void* const* d_in, const int* in_sizes, int n_in,
                              void* d_out, int out_size, void* d_ws, size_t ws_size,
                              hipStream_t stream) {
  const float* x   = (const float*)d_in[0];
  const float* Wq1 = (const float*)d_in[1];
  const float* Wq2 = (const float*)d_in[2];
  const float* bq  = (const float*)d_in[3];
  const float* Wk1 = (const float*)d_in[4];
  const float* Wk2 = (const float*)d_in[5];
  // d_in[6] = bk : drops out of softmax (row-constant logit shift)
  const float* Wv1 = (const float*)d_in[7];
  const float* Wv2 = (const float*)d_in[8];
  const float* bv  = (const float*)d_in[9];
  const float* Wo1 = (const float*)d_in[10];
  const float* Wo2 = (const float*)d_in[11];
  const float* bo  = (const float*)d_in[12];
  float* out = (float*)d_out;
  float* ws  = (float*)d_ws;

  if (ws_size < (size_t)5431424 * sizeof(float)) return;

  float* wm    = ws;
  float* b2s   = ws + 20480;
  float* xpq   = ws + 21120;
  float* kb    = ws + 117120;
  float* tbuf  = ws + 178560;
  ushort_t* qhb   = (ushort_t*)(ws + 274560);
  ushort_t* k1b   = (ushort_t*)(ws + 1257600);
  ushort_t* v1b   = (ushort_t*)(ws + 1306752);
  ushort_t* xb    = (ushort_t*)(ws + 1355904);
  ushort_t* wcatb = (ushort_t*)(ws + 3321984);
  ushort_t* wo1b  = (ushort_t*)(ws + 3403904);
  ushort_t* wv2b  = (ushort_t*)(ws + 3444864);
  ushort_t* wvb   = (ushort_t*)(ws + 3465344);

  prep_kernel<<<2080, 256, 0, stream>>>(x, Wq1, Wk1, Wv1, Wo1, Wq2, Wk2, Wv2, bq,
                                        xb, wcatb, wo1b, wv2b, wm, b2s);
  gemm_qkv_kernel<<<96, 128, 0, stream>>>(xb, wcatb, xpq, k1b, v1b);
  qh_kb_kernel<<<dim3(NT, 21, Bb), 256, 0, stream>>>(xpq, wm, b2s, k1b, qhb, kb);
  attn2_kernel<<<dim3(NI, Hh, Bb), 128, 0, stream>>>(qhb, k1b, v1b, wv2b, kb, bv, wvb);
  gemm_o1_kernel<<<96, 128, 0, stream>>>(wvb, wo1b, tbuf);
  proj_o2_kernel<<<dim3(188, 5), 256, 0, stream>>>(tbuf, Wo2, bo, out);
}

// Round 7
// 116.863 us; speedup vs baseline: 7.4453x; 1.0387x over previous
//
#include <hip/hip_runtime.h>
#include <math.h>

#define Bb 2
#define Ss 1500
#define SP 1536   // padded rows per batch (24 tiles of 64)
#define Nn 1280
#define Hh 20
#define Rr 32
#define NT 24     // key tiles of 64

typedef __attribute__((ext_vector_type(8))) short short8;
typedef __attribute__((ext_vector_type(4))) float f32x4;
typedef unsigned short ushort_t;

__device__ __forceinline__ unsigned short f2bf(float f) {
  unsigned u = __float_as_uint(f);
  u += 0x7fffu + ((u >> 16) & 1u);
  return (unsigned short)(u >> 16);
}
__device__ __forceinline__ float bf2f(unsigned short u) {
  return __uint_as_float((unsigned)u << 16);
}

__device__ __forceinline__ void gload16(const void* g, void* l) {
  __builtin_amdgcn_global_load_lds((const __attribute__((address_space(1))) unsigned int*)g,
                                   (__attribute__((address_space(3))) unsigned int*)l, 16, 0, 0);
}
__device__ __forceinline__ void gload4(const void* g, void* l) {
  __builtin_amdgcn_global_load_lds((const __attribute__((address_space(1))) unsigned int*)g,
                                   (__attribute__((address_space(3))) unsigned int*)l, 4, 0, 0);
}

#define BAR()                                  \
  do {                                         \
    asm volatile("" ::: "memory");             \
    __builtin_amdgcn_s_barrier();              \
    asm volatile("" ::: "memory");             \
  } while (0)

#define VMW(n) asm volatile("s_waitcnt vmcnt(" #n ")" ::: "memory")

// ---------------------------------------------------------------------------
// ws layout (float offsets) — round-4 layout, verified:
//   wm     0        (20480)    fp32 Wq2h@Wk2h / 8
//   b2s    20480    (640)      fp32 bq@Wk2h / 8
//   xpq    21120    (96000)    fp32 q1 [3000][32]
//   kb     117120   (61440)    fp32 [40][1536], -1e30 pad
//   tbuf   178560   (96000)    fp32 [3000][32]
//   qhb    274560   (983040)   bf16 [40][1536][32]
//   k1b    1257600  (49152)    bf16 [2][1536][32]
//   v1b    1306752  (49152)    bf16 [2][32][1536]
//   xb     1355904  (1966080)  bf16 [3072][1280]
//   wcatb  3321984  (81920)    bf16 [128][1280] (q|k|v|0)
//   wo1b   3403904  (40960)    bf16 [64][1280]  (Wo1|0)
//   wv2b   3444864  (20480)    bf16 [1280][32]
//   wvb    3465344  (1966080)  bf16 [3072][1280]
//   end    5431424 floats = 21.7 MB
// ---------------------------------------------------------------------------

// merged prep: blocks [0,1920): cast x; [1920,2060): cast weights; [2060,2080): wm/b2s
__global__ void prep_kernel(const float* __restrict__ x, const float* __restrict__ Wq1,
                            const float* __restrict__ Wk1, const float* __restrict__ Wv1,
                            const float* __restrict__ Wo1, const float* __restrict__ Wq2,
                            const float* __restrict__ Wk2, const float* __restrict__ Wv2,
                            const float* __restrict__ bq, ushort_t* __restrict__ xb,
                            ushort_t* __restrict__ wcatb, ushort_t* __restrict__ wo1b,
                            ushort_t* __restrict__ wv2b, float* __restrict__ wm,
                            float* __restrict__ b2s) {
  int bid = blockIdx.x, tid = threadIdx.x;
  __shared__ float q2s[2048], k2s[2048], bqs[64];
  if (bid < 1920) {
    int gid = bid * 256 + tid;  // 491520 = 3072*160
    int gr = gid / 160, c8 = gid % 160;
    int b = gr / SP, i = gr - b * SP;
    short8 v = (short8){0, 0, 0, 0, 0, 0, 0, 0};
    if (i < Ss) {
      const float* src = x + ((size_t)(b * Ss + i)) * 1280 + c8 * 8;
      float4 a0 = *(const float4*)src;
      float4 a1 = *(const float4*)(src + 4);
      v[0] = (short)f2bf(a0.x); v[1] = (short)f2bf(a0.y);
      v[2] = (short)f2bf(a0.z); v[3] = (short)f2bf(a0.w);
      v[4] = (short)f2bf(a1.x); v[5] = (short)f2bf(a1.y);
      v[6] = (short)f2bf(a1.z); v[7] = (short)f2bf(a1.w);
    }
    *(short8*)(xb + (size_t)gr * 1280 + c8 * 8) = v;
  } else if (bid < 2060) {
    int gid = (bid - 1920) * 256 + tid;  // 35840
    const float* src = nullptr;
    ushort_t* dst = nullptr;
    if (gid < 20480) {
      int row = gid / 160, c8 = gid % 160;
      dst = wcatb + (size_t)row * 1280 + c8 * 8;
      if (row < 32) src = Wq1 + (size_t)row * 1280 + c8 * 8;
      else if (row < 64) src = Wk1 + (size_t)(row - 32) * 1280 + c8 * 8;
      else if (row < 96) src = Wv1 + (size_t)(row - 64) * 1280 + c8 * 8;
    } else if (gid < 30720) {
      int g = gid - 20480;
      int row = g / 160, c8 = g % 160;
      dst = wo1b + (size_t)row * 1280 + c8 * 8;
      if (row < 32) src = Wo1 + (size_t)row * 1280 + c8 * 8;
    } else {
      int g = gid - 30720;
      int row = g >> 2, c8 = g & 3;
      dst = wv2b + row * 32 + c8 * 8;
      src = Wv2 + row * 32 + c8 * 8;
    }
    short8 v = (short8){0, 0, 0, 0, 0, 0, 0, 0};
    if (src) {
      #pragma unroll
      for (int j = 0; j < 8; ++j) v[j] = (short)f2bf(src[j]);
    }
    *(short8*)dst = v;
  } else {
    int h = bid - 2060;
    for (int e = tid; e < 2048; e += 256) {
      q2s[e] = Wq2[h * 2048 + e];
      k2s[e] = Wk2[h * 2048 + e];
    }
    if (tid < 64) bqs[tid] = bq[h * 64 + tid];
    __syncthreads();
    for (int e = tid; e < 1024; e += 256) {
      int r = e >> 5, t = e & 31;
      float s = 0.f;
      #pragma unroll 16
      for (int d = 0; d < 64; ++d) s += q2s[d * 32 + r] * k2s[d * 32 + t];
      wm[h * 1024 + r * 32 + t] = s * 0.125f;
    }
    if (tid < 32) {
      float s = 0.f;
      #pragma unroll 16
      for (int d = 0; d < 64; ++d) s += bqs[d] * k2s[d * 32 + tid];
      b2s[h * 32 + tid] = s * 0.125f;
    }
  }
}

// GEMM: xb[3072x1280]bf16 @ wcat[96x1280]^T -> q1 fp32 / k1 bf16 / v1T bf16
// rowtile 32, 2 waves x 16 rows x 6 frags, BK=64, XOR-swizzled LDS.
__global__ __launch_bounds__(128) void gemm_qkv_kernel(
    const ushort_t* __restrict__ xbg, const ushort_t* __restrict__ wcat,
    float* __restrict__ xpq, ushort_t* __restrict__ k1b, ushort_t* __restrict__ v1b) {
  int tid = threadIdx.x, w = tid >> 6, l = tid & 63, l15 = l & 15, l4 = l >> 4;
  int row0 = blockIdx.x * 32;
  __shared__ __align__(16) short As[2][2048];  // [32][64] swz
  __shared__ __align__(16) short Bs[2][6144];  // [96][64] swz
  int sw8 = (((l & 7) ^ ((l >> 3) & 7)) << 3);  // pre-swizzled chunk for staging
  const ushort_t* asrc0 = xbg + (size_t)(row0 + w * 16 + (l >> 3)) * 1280 + sw8;
  const ushort_t* asrc1 = asrc0 + (size_t)8 * 1280;
  const ushort_t* bsrc[6];
  #pragma unroll
  for (int g = 0; g < 6; ++g)
    bsrc[g] = wcat + (size_t)(w * 48 + g * 8 + (l >> 3)) * 1280 + sw8;

#define QSTAGE(bufi, kk)                                            \
  do {                                                              \
    gload16(asrc0 + (kk), &As[bufi][w * 1024]);                     \
    gload16(asrc1 + (kk), &As[bufi][w * 1024 + 512]);               \
    gload16(bsrc[0] + (kk), &Bs[bufi][w * 3072]);                   \
    gload16(bsrc[1] + (kk), &Bs[bufi][w * 3072 + 512]);             \
    gload16(bsrc[2] + (kk), &Bs[bufi][w * 3072 + 1024]);            \
    gload16(bsrc[3] + (kk), &Bs[bufi][w * 3072 + 1536]);            \
    gload16(bsrc[4] + (kk), &Bs[bufi][w * 3072 + 2048]);            \
    gload16(bsrc[5] + (kk), &Bs[bufi][w * 3072 + 2560]);            \
  } while (0)

  f32x4 acc[6];
  #pragma unroll
  for (int nf = 0; nf < 6; ++nf) acc[nf] = (f32x4){0.f, 0.f, 0.f, 0.f};

  QSTAGE(0, 0);
  int cur = 0;
  for (int t = 0; t < 20; ++t) {
    if (t < 19) {
      QSTAGE(cur ^ 1, (t + 1) * 64);
      VMW(8);
    } else {
      VMW(0);
    }
    BAR();
    #pragma unroll
    for (int ks = 0; ks < 2; ++ks) {
      short8 af = *(const short8*)&As[cur][(w * 16 + l15) * 64 +
                                           (((ks * 4 + l4) ^ (l15 & 7)) << 3)];
      #pragma unroll
      for (int nf = 0; nf < 6; ++nf) {
        short8 bf = *(const short8*)&Bs[cur][(nf * 16 + l15) * 64 +
                                             (((ks * 4 + l4) ^ (l15 & 7)) << 3)];
        acc[nf] = __builtin_amdgcn_mfma_f32_16x16x32_bf16(af, bf, acc[nf], 0, 0, 0);
      }
    }
    BAR();
    cur ^= 1;
  }
#undef QSTAGE

  #pragma unroll
  for (int nf = 0; nf < 6; ++nf) {
    int o = nf * 16 + l15;
    #pragma unroll
    for (int reg = 0; reg < 4; ++reg) {
      int gr = row0 + w * 16 + l4 * 4 + reg;
      int b = (gr >= SP) ? 1 : 0;
      int i = gr - b * SP;
      if (i < Ss) {
        float v = acc[nf][reg];
        if (o < 32) xpq[((size_t)b * Ss + i) * 32 + o] = v;
        else if (o < 64) k1b[((size_t)b * SP + i) * 32 + (o - 32)] = f2bf(v);
        else v1b[((size_t)b * 32 + (o - 64)) * SP + i] = f2bf(v);
      }
    }
  }
}

// merged: blockIdx.y<20 -> qh (per i-tile,h,b); blockIdx.y==20 -> kb (per j-tile,b)
__global__ void qh_kb_kernel(const float* __restrict__ xpq, const float* __restrict__ wm,
                             const float* __restrict__ b2s, const ushort_t* __restrict__ k1b,
                             ushort_t* __restrict__ qhb, float* __restrict__ kbp) {
  int tid = threadIdx.x, b = blockIdx.z;
  if (blockIdx.y == 20) {
    int j0 = blockIdx.x * 64;
    __shared__ float k1s[64 * 33];
    __shared__ float b2sh[20 * 33];
    for (int e = tid; e < 2048; e += 256) {
      int row = e >> 5, t = e & 31;
      k1s[row * 33 + t] = bf2f(k1b[((size_t)b * SP + j0 + row) * 32 + t]);
    }
    for (int e = tid; e < 640; e += 256) b2sh[(e >> 5) * 33 + (e & 31)] = b2s[e];
    __syncthreads();
    for (int e = tid; e < 1280; e += 256) {
      int h = e >> 6, rw = e & 63;
      int j = j0 + rw;
      float s = -1e30f;
      if (j < Ss) {
        s = 0.f;
        #pragma unroll 8
        for (int t = 0; t < 32; ++t) s += k1s[rw * 33 + t] * b2sh[h * 33 + t];
      }
      kbp[((size_t)b * Hh + h) * SP + j] = s;
    }
  } else {
    int it = blockIdx.x, h = blockIdx.y;
    int i0 = it * 64;
    __shared__ float q1s[64 * 33];
    __shared__ float wms[1024];
    for (int e = tid; e < 2048; e += 256) {
      int row = e >> 5, r = e & 31;
      int i = i0 + row;
      q1s[row * 33 + r] = (i < Ss) ? xpq[((size_t)b * Ss + i) * 32 + r] : 0.f;
    }
    for (int e = tid; e < 1024; e += 256) wms[e] = wm[h * 1024 + e];
    __syncthreads();
    int row = tid >> 2, tc = (tid & 3) * 8;
    float o[8];
    #pragma unroll
    for (int j = 0; j < 8; ++j) o[j] = 0.f;
    for (int r = 0; r < 32; ++r) {
      float qv = q1s[row * 33 + r];
      #pragma unroll
      for (int j = 0; j < 8; ++j) o[j] += qv * wms[r * 32 + tc + j];
    }
    short8 sv;
    #pragma unroll
    for (int j = 0; j < 8; ++j) sv[j] = (short)f2bf(o[j]);
    *(short8*)(qhb + ((size_t)(b * Hh + h) * SP + i0 + row) * 32 + tc) = sv;
  }
}

// Attention (round-3 verified version, 60 µs): per (i-tile, h, b).
// O = (P@v1)@Wv2h; P/PV1 relayout through per-wave swizzled LDS.
__global__ __launch_bounds__(256) void attn2_kernel(
    const ushort_t* __restrict__ qhg, const ushort_t* __restrict__ k1g,
    const ushort_t* __restrict__ v1g, const ushort_t* __restrict__ wv2g,
    const float* __restrict__ kbg, const float* __restrict__ bv, ushort_t* __restrict__ wvb) {
  int it = blockIdx.x, h = blockIdx.y, b = blockIdx.z;
  int bh = b * Hh + h;
  int i0 = it * 64;
  int tid = threadIdx.x, w = tid >> 6, l = tid & 63;
  int l15 = l & 15, l4 = l >> 4;

  __shared__ short kS[2][2048];  // [kchunk(4)][key(64)][8]
  __shared__ short vS[2][2048];  // [r(32)][jslot(8)^swz][8]
  __shared__ float kbS[2][64];
  __shared__ short pS[4][1024];  // per-wave P [q(16)][key-slot swz]
  __shared__ short p2S[4][512];  // per-wave PV1 [q(16)][r-slot swz]

  // resident A-frag: Qh[q=l15][k=l4*8+e]
  short8 qa = *(const short8*)(qhg + ((size_t)bh * SP + i0 + w * 16 + l15) * 32 + l4 * 8);
  // resident B-frags: Wv2h[r=l4*8+e][d=db*16+l15]
  short8 wb0 = *(const short8*)(wv2g + (size_t)(h * 64 + 0 * 16 + l15) * 32 + l4 * 8);
  short8 wb1 = *(const short8*)(wv2g + (size_t)(h * 64 + 1 * 16 + l15) * 32 + l4 * 8);
  short8 wb2 = *(const short8*)(wv2g + (size_t)(h * 64 + 2 * 16 + l15) * 32 + l4 * 8);
  short8 wb3 = *(const short8*)(wv2g + (size_t)(h * 64 + 3 * 16 + l15) * 32 + l4 * 8);
  VMW(0);  // qa/wb landed; vmcnt counting below exact

  const ushort_t* ksrc = k1g + (size_t)b * SP * 32 + l * 32 + w * 8;
  const ushort_t* vsrc =
      v1g + ((size_t)b * 32 + w * 8 + (l >> 3)) * SP + (((l & 7) ^ ((l >> 3) & 7)) << 3);
  const float* kbsrc = kbg + (size_t)bh * SP + l;

#define STAGE(bufi, tt)                                   \
  do {                                                    \
    int j0s = (tt) * 64;                                  \
    gload16(ksrc + (size_t)j0s * 32, &kS[bufi][w * 512]); \
    gload16(vsrc + j0s, &vS[bufi][w * 512]);              \
    if (w == 0) gload4(kbsrc + j0s, &kbS[bufi][0]);       \
  } while (0)

  STAGE(0, 0);

  f32x4 acc[4];
  #pragma unroll
  for (int db = 0; db < 4; ++db) acc[db] = (f32x4){0.f, 0.f, 0.f, 0.f};
  float psr[4] = {0.f, 0.f, 0.f, 0.f};
  const f32x4 zf = (f32x4){0.f, 0.f, 0.f, 0.f};

  int cur = 0;
  for (int t = 0; t < NT; ++t) {
    if (t < NT - 1) {
      STAGE(cur ^ 1, t + 1);
      if (w == 0) VMW(3); else VMW(2);
    } else {
      VMW(0);
    }
    BAR();

    // S = Qh @ K1^T (+kb), exp, pack to per-wave P
    #pragma unroll
    for (int nb = 0; nb < 4; ++nb) {
      short8 kf = *(const short8*)&kS[cur][l4 * 512 + (nb * 16 + l15) * 8];
      f32x4 c = __builtin_amdgcn_mfma_f32_16x16x32_bf16(qa, kf, zf, 0, 0, 0);
      float kbv = kbS[cur][nb * 16 + l15];
      int slot_lo = nb * 2 + (l15 >> 3);
      #pragma unroll
      for (int reg = 0; reg < 4; ++reg) {
        int q = l4 * 4 + reg;
        float p = __expf(c[reg] + kbv);
        unsigned short us = f2bf(p);
        psr[reg] += __uint_as_float((unsigned)us << 16);
        pS[w][q * 64 + ((slot_lo ^ (q & 7)) << 3) + (l15 & 7)] = (short)us;
      }
    }

    // PV1 = P @ v1  (16q x 32r)
    f32x4 pv1[2];
    pv1[0] = (f32x4){0.f, 0.f, 0.f, 0.f};
    pv1[1] = (f32x4){0.f, 0.f, 0.f, 0.f};
    #pragma unroll
    for (int kh = 0; kh < 2; ++kh) {
      short8 pa = *(const short8*)&pS[w][l15 * 64 + (((kh * 4 + l4) ^ (l15 & 7)) << 3)];
      #pragma unroll
      for (int nf = 0; nf < 2; ++nf) {
        short8 vf =
            *(const short8*)&vS[cur][(nf * 16 + l15) * 64 + (((kh * 4 + l4) ^ (l15 & 7)) << 3)];
        pv1[nf] = __builtin_amdgcn_mfma_f32_16x16x32_bf16(pa, vf, pv1[nf], 0, 0, 0);
      }
    }

    // relayout PV1 -> A-frag via per-wave LDS (swizzled slots)
    #pragma unroll
    for (int nf = 0; nf < 2; ++nf) {
      #pragma unroll
      for (int reg = 0; reg < 4; ++reg) {
        int q = l4 * 4 + reg;
        int slot = nf * 2 + (l15 >> 3);
        p2S[w][q * 32 + ((slot ^ ((q >> 1) & 3)) << 3) + (l15 & 7)] =
            (short)f2bf(pv1[nf][reg]);
      }
    }
    short8 pa2 = *(const short8*)&p2S[w][l15 * 32 + ((l4 ^ ((l15 >> 1) & 3)) << 3)];

    // O += PV1 @ Wv2h
    acc[0] = __builtin_amdgcn_mfma_f32_16x16x32_bf16(pa2, wb0, acc[0], 0, 0, 0);
    acc[1] = __builtin_amdgcn_mfma_f32_16x16x32_bf16(pa2, wb1, acc[1], 0, 0, 0);
    acc[2] = __builtin_amdgcn_mfma_f32_16x16x32_bf16(pa2, wb2, acc[2], 0, 0, 0);
    acc[3] = __builtin_amdgcn_mfma_f32_16x16x32_bf16(pa2, wb3, acc[3], 0, 0, 0);

    BAR();
    cur ^= 1;
  }
#undef STAGE

  #pragma unroll
  for (int reg = 0; reg < 4; ++reg) {
    #pragma unroll
    for (int m = 1; m < 16; m <<= 1) psr[reg] += __shfl_xor(psr[reg], m, 64);
  }
  float inv[4];
  #pragma unroll
  for (int reg = 0; reg < 4; ++reg) inv[reg] = 1.f / psr[reg];

  #pragma unroll
  for (int db = 0; db < 4; ++db) {
    float bvv = bv[h * 64 + db * 16 + l15];
    #pragma unroll
    for (int reg = 0; reg < 4; ++reg) {
      int qi = i0 + w * 16 + l4 * 4 + reg;
      if (qi < Ss)
        wvb[((size_t)(b * SP + qi)) * 1280 + h * 64 + db * 16 + l15] =
            f2bf(acc[db][reg] * inv[reg] + bvv);
    }
  }
}

// GEMM: wvb[3072x1280]bf16 @ wo1b[32x1280]^T -> tbuf fp32, rowtile 32, BK=64
__global__ __launch_bounds__(128) void gemm_o1_kernel(const ushort_t* __restrict__ wvg,
                                                      const ushort_t* __restrict__ wo1,
                                                      float* __restrict__ tbuf) {
  int tid = threadIdx.x, w = tid >> 6, l = tid & 63, l15 = l & 15, l4 = l >> 4;
  int row0 = blockIdx.x * 32;
  __shared__ __align__(16) short As[2][2048];
  __shared__ __align__(16) short Bs[2][2048];
  int sw8 = (((l & 7) ^ ((l >> 3) & 7)) << 3);
  const ushort_t* asrc0 = wvg + (size_t)(row0 + w * 16 + (l >> 3)) * 1280 + sw8;
  const ushort_t* asrc1 = asrc0 + (size_t)8 * 1280;
  const ushort_t* bsrc = wo1 + (size_t)(w * 16 + (l >> 3)) * 1280 + sw8;
  const ushort_t* bsrc1 = bsrc + (size_t)8 * 1280;

#define OSTAGE(bufi, kk)                                 \
  do {                                                   \
    gload16(asrc0 + (kk), &As[bufi][w * 1024]);          \
    gload16(asrc1 + (kk), &As[bufi][w * 1024 + 512]);    \
    gload16(bsrc + (kk), &Bs[bufi][w * 1024]);           \
    gload16(bsrc1 + (kk), &Bs[bufi][w * 1024 + 512]);    \
  } while (0)

  f32x4 acc[2];
  acc[0] = (f32x4){0.f, 0.f, 0.f, 0.f};
  acc[1] = (f32x4){0.f, 0.f, 0.f, 0.f};
  OSTAGE(0, 0);
  int cur = 0;
  for (int t = 0; t < 20; ++t) {
    if (t < 19) {
      OSTAGE(cur ^ 1, (t + 1) * 64);
      VMW(4);
    } else {
      VMW(0);
    }
    BAR();
    #pragma unroll
    for (int ks = 0; ks < 2; ++ks) {
      short8 af = *(const short8*)&As[cur][(w * 16 + l15) * 64 +
                                           (((ks * 4 + l4) ^ (l15 & 7)) << 3)];
      #pragma unroll
      for (int nf = 0; nf < 2; ++nf) {
        short8 bf = *(const short8*)&Bs[cur][(nf * 16 + l15) * 64 +
                                             (((ks * 4 + l4) ^ (l15 & 7)) << 3)];
        acc[nf] = __builtin_amdgcn_mfma_f32_16x16x32_bf16(af, bf, acc[nf], 0, 0, 0);
      }
    }
    BAR();
    cur ^= 1;
  }
#undef OSTAGE

  #pragma unroll
  for (int nf = 0; nf < 2; ++nf) {
    int o = nf * 16 + l15;
    #pragma unroll
    for (int reg = 0; reg < 4; ++reg) {
      int gr = row0 + w * 16 + l4 * 4 + reg;
      int b = (gr >= SP) ? 1 : 0;
      int i = gr - b * SP;
      if (i < Ss) tbuf[((size_t)b * Ss + i) * 32 + o] = acc[nf][reg];
    }
  }
}

// out[row][n] = bo[n] + sum_o tbuf[row][o] * Wo2[n][o]
__global__ void proj_o2_kernel(const float* __restrict__ tbuf, const float* __restrict__ Wo2,
                               const float* __restrict__ bo, float* __restrict__ out) {
  int rb = blockIdx.x, nb = blockIdx.y, tid = threadIdx.x;
  int rowbase = rb * 16, n0 = nb * 256;
  __shared__ float ts[16 * 33];
  __shared__ float wos[256 * 33];
  for (int e = tid; e < 8192; e += 256) {
    int nloc = e >> 5, o = e & 31;
    wos[nloc * 33 + o] = Wo2[(size_t)(n0 + nloc) * 32 + o];
  }
  for (int e = tid; e < 512; e += 256) {
    int row = e >> 5, o = e & 31;
    int gr = rowbase + row;
    ts[row * 33 + o] = (gr < Bb * Ss) ? tbuf[(size_t)gr * 32 + o] : 0.f;
  }
  __syncthreads();
  int n = n0 + tid;
  float bias = bo[n];
  for (int row = 0; row < 16; ++row) {
    int gr = rowbase + row;
    if (gr >= Bb * Ss) break;
    float s = bias;
    #pragma unroll 8
    for (int o = 0; o < 32; ++o) s += ts[row * 33 + o] * wos[tid * 33 + o];
    out[(size_t)gr * 1280 + n] = s;
  }
}

extern "C" void kernel_launch(void* const* d_in, const int* in_sizes, int n_in,
                              void* d_out, int out_size, void* d_ws, size_t ws_size,
                              hipStream_t stream) {
  const float* x   = (const float*)d_in[0];
  const float* Wq1 = (const float*)d_in[1];
  const float* Wq2 = (const float*)d_in[2];
  const float* bq  = (const float*)d_in[3];
  const float* Wk1 = (const float*)d_in[4];
  const float* Wk2 = (const float*)d_in[5];
  // d_in[6] = bk : drops out of softmax (row-constant logit shift)
  const float* Wv1 = (const float*)d_in[7];
  const float* Wv2 = (const float*)d_in[8];
  const float* bv  = (const float*)d_in[9];
  const float* Wo1 = (const float*)d_in[10];
  const float* Wo2 = (const float*)d_in[11];
  const float* bo  = (const float*)d_in[12];
  float* out = (float*)d_out;
  float* ws  = (float*)d_ws;

  if (ws_size < (size_t)5431424 * sizeof(float)) return;

  float* wm    = ws;
  float* b2s   = ws + 20480;
  float* xpq   = ws + 21120;
  float* kb    = ws + 117120;
  float* tbuf  = ws + 178560;
  ushort_t* qhb   = (ushort_t*)(ws + 274560);
  ushort_t* k1b   = (ushort_t*)(ws + 1257600);
  ushort_t* v1b   = (ushort_t*)(ws + 1306752);
  ushort_t* xb    = (ushort_t*)(ws + 1355904);
  ushort_t* wcatb = (ushort_t*)(ws + 3321984);
  ushort_t* wo1b  = (ushort_t*)(ws + 3403904);
  ushort_t* wv2b  = (ushort_t*)(ws + 3444864);
  ushort_t* wvb   = (ushort_t*)(ws + 3465344);

  prep_kernel<<<2080, 256, 0, stream>>>(x, Wq1, Wk1, Wv1, Wo1, Wq2, Wk2, Wv2, bq,
                                        xb, wcatb, wo1b, wv2b, wm, b2s);
  gemm_qkv_kernel<<<96, 128, 0, stream>>>(xb, wcatb, xpq, k1b, v1b);
  qh_kb_kernel<<<dim3(NT, 21, Bb), 256, 0, stream>>>(xpq, wm, b2s, k1b, qhb, kb);
  attn2_kernel<<<dim3(NT, Hh, Bb), 256, 0, stream>>>(qhb, k1b, v1b, wv2b, kb, bv, wvb);
  gemm_o1_kernel<<<96, 128, 0, stream>>>(wvb, wo1b, tbuf);
  proj_o2_kernel<<<dim3(188, 5), 256, 0, stream>>>(tbuf, Wo2, bo, out);
}

// Round 8
// 104.173 us; speedup vs baseline: 8.3522x; 1.1218x over previous
//
#include <hip/hip_runtime.h>
#include <math.h>

#define Bb 2
#define Ss 1500
#define SP 1536   // padded rows per batch (24 tiles of 64)
#define Nn 1280
#define Hh 20
#define Rr 32
#define NT 24     // key tiles of 64

#define LOG2E 1.44269504088896f

typedef __attribute__((ext_vector_type(8))) short short8;
typedef __attribute__((ext_vector_type(4))) float f32x4;
typedef unsigned short ushort_t;

__device__ __forceinline__ unsigned short f2bf(float f) {
  unsigned u = __float_as_uint(f);
  u += 0x7fffu + ((u >> 16) & 1u);
  return (unsigned short)(u >> 16);
}
__device__ __forceinline__ float bf2f(unsigned short u) {
  return __uint_as_float((unsigned)u << 16);
}
__device__ __forceinline__ unsigned cvtpk(float a, float b) {
  unsigned d;
  asm("v_cvt_pk_bf16_f32 %0, %1, %2" : "=v"(d) : "v"(a), "v"(b));
  return d;  // lo16=bf16(a), hi16=bf16(b), RNE
}
__device__ __forceinline__ float fexp2(float x) {
  float r;
  asm("v_exp_f32 %0, %1" : "=v"(r) : "v"(x));
  return r;
}

__device__ __forceinline__ void gload16(const void* g, void* l) {
  __builtin_amdgcn_global_load_lds((const __attribute__((address_space(1))) unsigned int*)g,
                                   (__attribute__((address_space(3))) unsigned int*)l, 16, 0, 0);
}
__device__ __forceinline__ void gload4(const void* g, void* l) {
  __builtin_amdgcn_global_load_lds((const __attribute__((address_space(1))) unsigned int*)g,
                                   (__attribute__((address_space(3))) unsigned int*)l, 4, 0, 0);
}

#define BAR()                                  \
  do {                                         \
    asm volatile("" ::: "memory");             \
    __builtin_amdgcn_s_barrier();              \
    asm volatile("" ::: "memory");             \
  } while (0)

#define VMW(n) asm volatile("s_waitcnt vmcnt(" #n ")" ::: "memory")

// ---------------------------------------------------------------------------
// ws layout (float offsets) — round-4/7 layout, verified:
//   wm     0        (20480)    fp32 Wq2h@Wk2h * 0.125*log2e
//   b2s    20480    (640)      fp32 bq@Wk2h * 0.125*log2e
//   xpq    21120    (96000)    fp32 q1 [3000][32]
//   kb     117120   (61440)    fp32 [40][1536], -1e30 pad
//   tbuf   178560   (96000)    fp32 [3000][32]
//   qhb    274560   (983040)   bf16 [40][1536][32]
//   k1b    1257600  (49152)    bf16 [2][1536][32]
//   v1b    1306752  (49152)    bf16 [2][32][1536]
//   xb     1355904  (1966080)  bf16 [3072][1280]
//   wcatb  3321984  (81920)    bf16 [128][1280] (q|k|v|0)
//   wo1b   3403904  (40960)    bf16 [64][1280]  (Wo1|0)
//   wv2b   3444864  (20480)    bf16 [1280][32]
//   wvb    3465344  (1966080)  bf16 [3072][1280]
//   end    5431424 floats = 21.7 MB
// ---------------------------------------------------------------------------

// merged prep: blocks [0,1920): cast x; [1920,2060): cast weights; [2060,2080): wm/b2s
__global__ void prep_kernel(const float* __restrict__ x, const float* __restrict__ Wq1,
                            const float* __restrict__ Wk1, const float* __restrict__ Wv1,
                            const float* __restrict__ Wo1, const float* __restrict__ Wq2,
                            const float* __restrict__ Wk2, const float* __restrict__ Wv2,
                            const float* __restrict__ bq, ushort_t* __restrict__ xb,
                            ushort_t* __restrict__ wcatb, ushort_t* __restrict__ wo1b,
                            ushort_t* __restrict__ wv2b, float* __restrict__ wm,
                            float* __restrict__ b2s) {
  int bid = blockIdx.x, tid = threadIdx.x;
  __shared__ float q2s[2048], k2s[2048], bqs[64];
  if (bid < 1920) {
    int gid = bid * 256 + tid;  // 491520 = 3072*160
    int gr = gid / 160, c8 = gid % 160;
    int b = gr / SP, i = gr - b * SP;
    short8 v = (short8){0, 0, 0, 0, 0, 0, 0, 0};
    if (i < Ss) {
      const float* src = x + ((size_t)(b * Ss + i)) * 1280 + c8 * 8;
      float4 a0 = *(const float4*)src;
      float4 a1 = *(const float4*)(src + 4);
      v[0] = (short)f2bf(a0.x); v[1] = (short)f2bf(a0.y);
      v[2] = (short)f2bf(a0.z); v[3] = (short)f2bf(a0.w);
      v[4] = (short)f2bf(a1.x); v[5] = (short)f2bf(a1.y);
      v[6] = (short)f2bf(a1.z); v[7] = (short)f2bf(a1.w);
    }
    *(short8*)(xb + (size_t)gr * 1280 + c8 * 8) = v;
  } else if (bid < 2060) {
    int gid = (bid - 1920) * 256 + tid;  // 35840
    const float* src = nullptr;
    ushort_t* dst = nullptr;
    if (gid < 20480) {
      int row = gid / 160, c8 = gid % 160;
      dst = wcatb + (size_t)row * 1280 + c8 * 8;
      if (row < 32) src = Wq1 + (size_t)row * 1280 + c8 * 8;
      else if (row < 64) src = Wk1 + (size_t)(row - 32) * 1280 + c8 * 8;
      else if (row < 96) src = Wv1 + (size_t)(row - 64) * 1280 + c8 * 8;
    } else if (gid < 30720) {
      int g = gid - 20480;
      int row = g / 160, c8 = g % 160;
      dst = wo1b + (size_t)row * 1280 + c8 * 8;
      if (row < 32) src = Wo1 + (size_t)row * 1280 + c8 * 8;
    } else {
      int g = gid - 30720;
      int row = g >> 2, c8 = g & 3;
      dst = wv2b + row * 32 + c8 * 8;
      src = Wv2 + row * 32 + c8 * 8;
    }
    short8 v = (short8){0, 0, 0, 0, 0, 0, 0, 0};
    if (src) {
      #pragma unroll
      for (int j = 0; j < 8; ++j) v[j] = (short)f2bf(src[j]);
    }
    *(short8*)dst = v;
  } else {
    int h = bid - 2060;
    for (int e = tid; e < 2048; e += 256) {
      q2s[e] = Wq2[h * 2048 + e];
      k2s[e] = Wk2[h * 2048 + e];
    }
    if (tid < 64) bqs[tid] = bq[h * 64 + tid];
    __syncthreads();
    for (int e = tid; e < 1024; e += 256) {
      int r = e >> 5, t = e & 31;
      float s = 0.f;
      #pragma unroll 16
      for (int d = 0; d < 64; ++d) s += q2s[d * 32 + r] * k2s[d * 32 + t];
      wm[h * 1024 + r * 32 + t] = s * (0.125f * LOG2E);  // exp2-direct scaling
    }
    if (tid < 32) {
      float s = 0.f;
      #pragma unroll 16
      for (int d = 0; d < 64; ++d) s += bqs[d] * k2s[d * 32 + tid];
      b2s[h * 32 + tid] = s * (0.125f * LOG2E);
    }
  }
}

// GEMM: xb[3072x1280]bf16 @ wcat[96x1280]^T -> q1 fp32 / k1 bf16 / v1T bf16
// rowtile 32, 2 waves x 16 rows x 6 frags, BK=64, XOR-swizzled LDS.
__global__ __launch_bounds__(128) void gemm_qkv_kernel(
    const ushort_t* __restrict__ xbg, const ushort_t* __restrict__ wcat,
    float* __restrict__ xpq, ushort_t* __restrict__ k1b, ushort_t* __restrict__ v1b) {
  int tid = threadIdx.x, w = tid >> 6, l = tid & 63, l15 = l & 15, l4 = l >> 4;
  int row0 = blockIdx.x * 32;
  __shared__ __align__(16) short As[2][2048];  // [32][64] swz
  __shared__ __align__(16) short Bs[2][6144];  // [96][64] swz
  int sw8 = (((l & 7) ^ ((l >> 3) & 7)) << 3);  // pre-swizzled chunk for staging
  const ushort_t* asrc0 = xbg + (size_t)(row0 + w * 16 + (l >> 3)) * 1280 + sw8;
  const ushort_t* asrc1 = asrc0 + (size_t)8 * 1280;
  const ushort_t* bsrc[6];
  #pragma unroll
  for (int g = 0; g < 6; ++g)
    bsrc[g] = wcat + (size_t)(w * 48 + g * 8 + (l >> 3)) * 1280 + sw8;

#define QSTAGE(bufi, kk)                                            \
  do {                                                              \
    gload16(asrc0 + (kk), &As[bufi][w * 1024]);                     \
    gload16(asrc1 + (kk), &As[bufi][w * 1024 + 512]);               \
    gload16(bsrc[0] + (kk), &Bs[bufi][w * 3072]);                   \
    gload16(bsrc[1] + (kk), &Bs[bufi][w * 3072 + 512]);             \
    gload16(bsrc[2] + (kk), &Bs[bufi][w * 3072 + 1024]);            \
    gload16(bsrc[3] + (kk), &Bs[bufi][w * 3072 + 1536]);            \
    gload16(bsrc[4] + (kk), &Bs[bufi][w * 3072 + 2048]);            \
    gload16(bsrc[5] + (kk), &Bs[bufi][w * 3072 + 2560]);            \
  } while (0)

  f32x4 acc[6];
  #pragma unroll
  for (int nf = 0; nf < 6; ++nf) acc[nf] = (f32x4){0.f, 0.f, 0.f, 0.f};

  QSTAGE(0, 0);
  int cur = 0;
  for (int t = 0; t < 20; ++t) {
    if (t < 19) {
      QSTAGE(cur ^ 1, (t + 1) * 64);
      VMW(8);
    } else {
      VMW(0);
    }
    BAR();
    #pragma unroll
    for (int ks = 0; ks < 2; ++ks) {
      short8 af = *(const short8*)&As[cur][(w * 16 + l15) * 64 +
                                           (((ks * 4 + l4) ^ (l15 & 7)) << 3)];
      #pragma unroll
      for (int nf = 0; nf < 6; ++nf) {
        short8 bf = *(const short8*)&Bs[cur][(nf * 16 + l15) * 64 +
                                             (((ks * 4 + l4) ^ (l15 & 7)) << 3)];
        acc[nf] = __builtin_amdgcn_mfma_f32_16x16x32_bf16(af, bf, acc[nf], 0, 0, 0);
      }
    }
    BAR();
    cur ^= 1;
  }
#undef QSTAGE

  #pragma unroll
  for (int nf = 0; nf < 6; ++nf) {
    int o = nf * 16 + l15;
    #pragma unroll
    for (int reg = 0; reg < 4; ++reg) {
      int gr = row0 + w * 16 + l4 * 4 + reg;
      int b = (gr >= SP) ? 1 : 0;
      int i = gr - b * SP;
      if (i < Ss) {
        float v = acc[nf][reg];
        if (o < 32) xpq[((size_t)b * Ss + i) * 32 + o] = v;
        else if (o < 64) k1b[((size_t)b * SP + i) * 32 + (o - 32)] = f2bf(v);
        else v1b[((size_t)b * 32 + (o - 64)) * SP + i] = f2bf(v);
      }
    }
  }
}

// merged: blockIdx.y<20 -> qh (per i-tile,h,b); blockIdx.y==20 -> kb (per j-tile,b)
__global__ void qh_kb_kernel(const float* __restrict__ xpq, const float* __restrict__ wm,
                             const float* __restrict__ b2s, const ushort_t* __restrict__ k1b,
                             ushort_t* __restrict__ qhb, float* __restrict__ kbp) {
  int tid = threadIdx.x, b = blockIdx.z;
  if (blockIdx.y == 20) {
    int j0 = blockIdx.x * 64;
    __shared__ float k1s[64 * 33];
    __shared__ float b2sh[20 * 33];
    for (int e = tid; e < 2048; e += 256) {
      int row = e >> 5, t = e & 31;
      k1s[row * 33 + t] = bf2f(k1b[((size_t)b * SP + j0 + row) * 32 + t]);
    }
    for (int e = tid; e < 640; e += 256) b2sh[(e >> 5) * 33 + (e & 31)] = b2s[e];
    __syncthreads();
    for (int e = tid; e < 1280; e += 256) {
      int h = e >> 6, rw = e & 63;
      int j = j0 + rw;
      float s = -1e30f;
      if (j < Ss) {
        s = 0.f;
        #pragma unroll 8
        for (int t = 0; t < 32; ++t) s += k1s[rw * 33 + t] * b2sh[h * 33 + t];
      }
      kbp[((size_t)b * Hh + h) * SP + j] = s;
    }
  } else {
    int it = blockIdx.x, h = blockIdx.y;
    int i0 = it * 64;
    __shared__ float q1s[64 * 33];
    __shared__ float wms[1024];
    for (int e = tid; e < 2048; e += 256) {
      int row = e >> 5, r = e & 31;
      int i = i0 + row;
      q1s[row * 33 + r] = (i < Ss) ? xpq[((size_t)b * Ss + i) * 32 + r] : 0.f;
    }
    for (int e = tid; e < 1024; e += 256) wms[e] = wm[h * 1024 + e];
    __syncthreads();
    int row = tid >> 2, tc = (tid & 3) * 8;
    float o[8];
    #pragma unroll
    for (int j = 0; j < 8; ++j) o[j] = 0.f;
    for (int r = 0; r < 32; ++r) {
      float qv = q1s[row * 33 + r];
      #pragma unroll
      for (int j = 0; j < 8; ++j) o[j] += qv * wms[r * 32 + tc + j];
    }
    short8 sv;
    #pragma unroll
    for (int j = 0; j < 8; ++j) sv[j] = (short)f2bf(o[j]);
    *(short8*)(qhb + ((size_t)(b * Hh + h) * SP + i0 + row) * 32 + tc) = sv;
  }
}

// Attention: round-3 verified structure; deltas this round:
//  - pv1 persistent fp32 accumulator; relayout+PV2 once in epilogue
//  - cvtpk(p,p)+ds_write_b16 low-half pack (1 VALU)
//  - psum uses unrounded p
//  - exp2-direct (log2e folded into wm/b2s upstream)
__global__ __launch_bounds__(256) void attn2_kernel(
    const ushort_t* __restrict__ qhg, const ushort_t* __restrict__ k1g,
    const ushort_t* __restrict__ v1g, const ushort_t* __restrict__ wv2g,
    const float* __restrict__ kbg, const float* __restrict__ bv, ushort_t* __restrict__ wvb) {
  int it = blockIdx.x, h = blockIdx.y, b = blockIdx.z;
  int bh = b * Hh + h;
  int i0 = it * 64;
  int tid = threadIdx.x, w = tid >> 6, l = tid & 63;
  int l15 = l & 15, l4 = l >> 4;

  __shared__ short kS[2][2048];  // [kchunk(4)][key(64)][8]
  __shared__ short vS[2][2048];  // [r(32)][jslot(8)^swz][8]
  __shared__ float kbS[2][64];
  __shared__ short pS[4][1024];  // per-wave P [q(16)][key-slot swz]
  __shared__ short p2S[4][512];  // per-wave PV1 [q(16)][r-slot swz]

  // resident A-frag: Qh[q=l15][k=l4*8+e]
  short8 qa = *(const short8*)(qhg + ((size_t)bh * SP + i0 + w * 16 + l15) * 32 + l4 * 8);
  // resident B-frags: Wv2h[r=l4*8+e][d=db*16+l15]
  short8 wb0 = *(const short8*)(wv2g + (size_t)(h * 64 + 0 * 16 + l15) * 32 + l4 * 8);
  short8 wb1 = *(const short8*)(wv2g + (size_t)(h * 64 + 1 * 16 + l15) * 32 + l4 * 8);
  short8 wb2 = *(const short8*)(wv2g + (size_t)(h * 64 + 2 * 16 + l15) * 32 + l4 * 8);
  short8 wb3 = *(const short8*)(wv2g + (size_t)(h * 64 + 3 * 16 + l15) * 32 + l4 * 8);
  VMW(0);  // qa/wb landed; vmcnt counting below exact

  const ushort_t* ksrc = k1g + (size_t)b * SP * 32 + l * 32 + w * 8;
  const ushort_t* vsrc =
      v1g + ((size_t)b * 32 + w * 8 + (l >> 3)) * SP + (((l & 7) ^ ((l >> 3) & 7)) << 3);
  const float* kbsrc = kbg + (size_t)bh * SP + l;

#define STAGE(bufi, tt)                                   \
  do {                                                    \
    int j0s = (tt) * 64;                                  \
    gload16(ksrc + (size_t)j0s * 32, &kS[bufi][w * 512]); \
    gload16(vsrc + j0s, &vS[bufi][w * 512]);              \
    if (w == 0) gload4(kbsrc + j0s, &kbS[bufi][0]);       \
  } while (0)

  STAGE(0, 0);

  f32x4 pv1[2];
  pv1[0] = (f32x4){0.f, 0.f, 0.f, 0.f};
  pv1[1] = (f32x4){0.f, 0.f, 0.f, 0.f};
  float psr[4] = {0.f, 0.f, 0.f, 0.f};
  const f32x4 zf = (f32x4){0.f, 0.f, 0.f, 0.f};

  int cur = 0;
  for (int t = 0; t < NT; ++t) {
    if (t < NT - 1) {
      STAGE(cur ^ 1, t + 1);
      if (w == 0) VMW(3); else VMW(2);
    } else {
      VMW(0);
    }
    BAR();

    // S = Qh @ K1^T (+kb), exp2, pack to per-wave P (b16 low-half writes)
    #pragma unroll
    for (int nb = 0; nb < 4; ++nb) {
      short8 kf = *(const short8*)&kS[cur][l4 * 512 + (nb * 16 + l15) * 8];
      f32x4 c = __builtin_amdgcn_mfma_f32_16x16x32_bf16(qa, kf, zf, 0, 0, 0);
      float kbv = kbS[cur][nb * 16 + l15];
      int slot_lo = nb * 2 + (l15 >> 3);
      #pragma unroll
      for (int reg = 0; reg < 4; ++reg) {
        int q = l4 * 4 + reg;
        float p = fexp2(c[reg] + kbv);
        psr[reg] += p;
        pS[w][q * 64 + ((slot_lo ^ (q & 7)) << 3) + (l15 & 7)] = (short)cvtpk(p, p);
      }
    }

    // PV1 += P @ v1 (16q x 32r), fp32 accumulation across all tiles
    #pragma unroll
    for (int kh = 0; kh < 2; ++kh) {
      short8 pa = *(const short8*)&pS[w][l15 * 64 + (((kh * 4 + l4) ^ (l15 & 7)) << 3)];
      #pragma unroll
      for (int nf = 0; nf < 2; ++nf) {
        short8 vf =
            *(const short8*)&vS[cur][(nf * 16 + l15) * 64 + (((kh * 4 + l4) ^ (l15 & 7)) << 3)];
        pv1[nf] = __builtin_amdgcn_mfma_f32_16x16x32_bf16(pa, vf, pv1[nf], 0, 0, 0);
      }
    }

    BAR();
    cur ^= 1;
  }
#undef STAGE

  // epilogue: relayout PV1 -> A-frag via per-wave LDS (once), then PV2
  #pragma unroll
  for (int nf = 0; nf < 2; ++nf) {
    #pragma unroll
    for (int reg = 0; reg < 4; ++reg) {
      int q = l4 * 4 + reg;
      int slot = nf * 2 + (l15 >> 3);
      p2S[w][q * 32 + ((slot ^ ((q >> 1) & 3)) << 3) + (l15 & 7)] =
          (short)cvtpk(pv1[nf][reg], pv1[nf][reg]);
    }
  }
  short8 pa2 = *(const short8*)&p2S[w][l15 * 32 + ((l4 ^ ((l15 >> 1) & 3)) << 3)];

  f32x4 acc[4];
  acc[0] = __builtin_amdgcn_mfma_f32_16x16x32_bf16(pa2, wb0, zf, 0, 0, 0);
  acc[1] = __builtin_amdgcn_mfma_f32_16x16x32_bf16(pa2, wb1, zf, 0, 0, 0);
  acc[2] = __builtin_amdgcn_mfma_f32_16x16x32_bf16(pa2, wb2, zf, 0, 0, 0);
  acc[3] = __builtin_amdgcn_mfma_f32_16x16x32_bf16(pa2, wb3, zf, 0, 0, 0);

  #pragma unroll
  for (int reg = 0; reg < 4; ++reg) {
    #pragma unroll
    for (int m = 1; m < 16; m <<= 1) psr[reg] += __shfl_xor(psr[reg], m, 64);
  }
  float inv[4];
  #pragma unroll
  for (int reg = 0; reg < 4; ++reg) inv[reg] = 1.f / psr[reg];

  #pragma unroll
  for (int db = 0; db < 4; ++db) {
    float bvv = bv[h * 64 + db * 16 + l15];
    #pragma unroll
    for (int reg = 0; reg < 4; ++reg) {
      int qi = i0 + w * 16 + l4 * 4 + reg;
      if (qi < Ss)
        wvb[((size_t)(b * SP + qi)) * 1280 + h * 64 + db * 16 + l15] =
            f2bf(acc[db][reg] * inv[reg] + bvv);
    }
  }
}

// GEMM: wvb[3072x1280]bf16 @ wo1b[32x1280]^T -> tbuf fp32, rowtile 32, BK=64
__global__ __launch_bounds__(128) void gemm_o1_kernel(const ushort_t* __restrict__ wvg,
                                                      const ushort_t* __restrict__ wo1,
                                                      float* __restrict__ tbuf) {
  int tid = threadIdx.x, w = tid >> 6, l = tid & 63, l15 = l & 15, l4 = l >> 4;
  int row0 = blockIdx.x * 32;
  __shared__ __align__(16) short As[2][2048];
  __shared__ __align__(16) short Bs[2][2048];
  int sw8 = (((l & 7) ^ ((l >> 3) & 7)) << 3);
  const ushort_t* asrc0 = wvg + (size_t)(row0 + w * 16 + (l >> 3)) * 1280 + sw8;
  const ushort_t* asrc1 = asrc0 + (size_t)8 * 1280;
  const ushort_t* bsrc = wo1 + (size_t)(w * 16 + (l >> 3)) * 1280 + sw8;
  const ushort_t* bsrc1 = bsrc + (size_t)8 * 1280;

#define OSTAGE(bufi, kk)                                 \
  do {                                                   \
    gload16(asrc0 + (kk), &As[bufi][w * 1024]);          \
    gload16(asrc1 + (kk), &As[bufi][w * 1024 + 512]);    \
    gload16(bsrc + (kk), &Bs[bufi][w * 1024]);           \
    gload16(bsrc1 + (kk), &Bs[bufi][w * 1024 + 512]);    \
  } while (0)

  f32x4 acc[2];
  acc[0] = (f32x4){0.f, 0.f, 0.f, 0.f};
  acc[1] = (f32x4){0.f, 0.f, 0.f, 0.f};
  OSTAGE(0, 0);
  int cur = 0;
  for (int t = 0; t < 20; ++t) {
    if (t < 19) {
      OSTAGE(cur ^ 1, (t + 1) * 64);
      VMW(4);
    } else {
      VMW(0);
    }
    BAR();
    #pragma unroll
    for (int ks = 0; ks < 2; ++ks) {
      short8 af = *(const short8*)&As[cur][(w * 16 + l15) * 64 +
                                           (((ks * 4 + l4) ^ (l15 & 7)) << 3)];
      #pragma unroll
      for (int nf = 0; nf < 2; ++nf) {
        short8 bf = *(const short8*)&Bs[cur][(nf * 16 + l15) * 64 +
                                             (((ks * 4 + l4) ^ (l15 & 7)) << 3)];
        acc[nf] = __builtin_amdgcn_mfma_f32_16x16x32_bf16(af, bf, acc[nf], 0, 0, 0);
      }
    }
    BAR();
    cur ^= 1;
  }
#undef OSTAGE

  #pragma unroll
  for (int nf = 0; nf < 2; ++nf) {
    int o = nf * 16 + l15;
    #pragma unroll
    for (int reg = 0; reg < 4; ++reg) {
      int gr = row0 + w * 16 + l4 * 4 + reg;
      int b = (gr >= SP) ? 1 : 0;
      int i = gr - b * SP;
      if (i < Ss) tbuf[((size_t)b * Ss + i) * 32 + o] = acc[nf][reg];
    }
  }
}

// out[row][n] = bo[n] + sum_o tbuf[row][o] * Wo2[n][o]
__global__ void proj_o2_kernel(const float* __restrict__ tbuf, const float* __restrict__ Wo2,
                               const float* __restrict__ bo, float* __restrict__ out) {
  int rb = blockIdx.x, nb = blockIdx.y, tid = threadIdx.x;
  int rowbase = rb * 16, n0 = nb * 256;
  __shared__ float ts[16 * 33];
  __shared__ float wos[256 * 33];
  for (int e = tid; e < 8192; e += 256) {
    int nloc = e >> 5, o = e & 31;
    wos[nloc * 33 + o] = Wo2[(size_t)(n0 + nloc) * 32 + o];
  }
  for (int e = tid; e < 512; e += 256) {
    int row = e >> 5, o = e & 31;
    int gr = rowbase + row;
    ts[row * 33 + o] = (gr < Bb * Ss) ? tbuf[(size_t)gr * 32 + o] : 0.f;
  }
  __syncthreads();
  int n = n0 + tid;
  float bias = bo[n];
  for (int row = 0; row < 16; ++row) {
    int gr = rowbase + row;
    if (gr >= Bb * Ss) break;
    float s = bias;
    #pragma unroll 8
    for (int o = 0; o < 32; ++o) s += ts[row * 33 + o] * wos[tid * 33 + o];
    out[(size_t)gr * 1280 + n] = s;
  }
}

extern "C" void kernel_launch(void* const* d_in, const int* in_sizes, int n_in,
                              void* d_out, int out_size, void* d_ws, size_t ws_size,
                              hipStream_t stream) {
  const float* x   = (const float*)d_in[0];
  const float* Wq1 = (const float*)d_in[1];
  const float* Wq2 = (const float*)d_in[2];
  const float* bq  = (const float*)d_in[3];
  const float* Wk1 = (const float*)d_in[4];
  const float* Wk2 = (const float*)d_in[5];
  // d_in[6] = bk : drops out of softmax (row-constant logit shift)
  const float* Wv1 = (const float*)d_in[7];
  const float* Wv2 = (const float*)d_in[8];
  const float* bv  = (const float*)d_in[9];
  const float* Wo1 = (const float*)d_in[10];
  const float* Wo2 = (const float*)d_in[11];
  const float* bo  = (const float*)d_in[12];
  float* out = (float*)d_out;
  float* ws  = (float*)d_ws;

  if (ws_size < (size_t)5431424 * sizeof(float)) return;

  float* wm    = ws;
  float* b2s   = ws + 20480;
  float* xpq   = ws + 21120;
  float* kb    = ws + 117120;
  float* tbuf  = ws + 178560;
  ushort_t* qhb   = (ushort_t*)(ws + 274560);
  ushort_t* k1b   = (ushort_t*)(ws + 1257600);
  ushort_t* v1b   = (ushort_t*)(ws + 1306752);
  ushort_t* xb    = (ushort_t*)(ws + 1355904);
  ushort_t* wcatb = (ushort_t*)(ws + 3321984);
  ushort_t* wo1b  = (ushort_t*)(ws + 3403904);
  ushort_t* wv2b  = (ushort_t*)(ws + 3444864);
  ushort_t* wvb   = (ushort_t*)(ws + 3465344);

  prep_kernel<<<2080, 256, 0, stream>>>(x, Wq1, Wk1, Wv1, Wo1, Wq2, Wk2, Wv2, bq,
                                        xb, wcatb, wo1b, wv2b, wm, b2s);
  gemm_qkv_kernel<<<96, 128, 0, stream>>>(xb, wcatb, xpq, k1b, v1b);
  qh_kb_kernel<<<dim3(NT, 21, Bb), 256, 0, stream>>>(xpq, wm, b2s, k1b, qhb, kb);
  attn2_kernel<<<dim3(NT, Hh, Bb), 256, 0, stream>>>(qhb, k1b, v1b, wv2b, kb, bv, wvb);
  gemm_o1_kernel<<<96, 128, 0, stream>>>(wvb, wo1b, tbuf);
  proj_o2_kernel<<<dim3(188, 5), 256, 0, stream>>>(tbuf, Wo2, bo, out);
}